// Round 11
// baseline (4967.016 us; speedup 1.0000x reference)
//
#include <hip/hip_runtime.h>
#include <math.h>

#define B_ 256
#define T_ 200
#define H_ 256
#define DOF_ 12

typedef __bf16 bf16;
typedef __bf16 bf16x8 __attribute__((ext_vector_type(8)));
typedef float f32x4 __attribute__((ext_vector_type(4)));
typedef unsigned long long u64;

#define XK 288      // gate GEMM K: 256 h + 12 prev + 20 zero pad
#define XPAD 296
#define P1PAD 264

#define PI_D 3.14159265358979323846

// ---- workspace byte offsets (all 16B aligned) ----
#define OFF_TF     0u
#define OFF_TCONP  10400u
#define OFF_ZCP    829600u
#define OFF_H0     1878176u
#define OFF_C0     2140320u
#define OFF_WCOMB  2402464u
#define OFF_WP1    2992288u
#define OFF_WP2    3123360u
#define OFF_WO1    3131552u
#define OFF_WO2    3262624u
#define OFF_WV     3270816u
#define OFF_HX     3295392u    // 16 pairs * 2 slots * 2 halves * 128 * 4 * 16B = 512KB
#define OFF_HSEQ   3819680u    // 256*200*256*2 = 26214400 (end ~30.0MB)

__device__ __forceinline__ float sigf(float x) { return 1.f / (1.f + __expf(-x)); }
__device__ __forceinline__ float tanh_f(float x) {
  float a = fabsf(x);
  float e = __expf(-2.f * a);
  float t = (1.f - e) * __builtin_amdgcn_rcpf(1.f + e);
  return x < 0.f ? -t : t;
}

// light barrier: order LDS, leave global ops in flight
#define LBAR() asm volatile("s_waitcnt lgkmcnt(0)\n\ts_barrier" ::: "memory")

// ---------------- time features [T,13] ----------------
__global__ void k_tfeat(float* tf) {
  int i = blockIdx.x * blockDim.x + threadIdx.x;
  if (i >= T_ * 13) return;
  int t = i / 13, j = i % 13;
  float tv = (float)t / 199.f;
  float v;
  if (j == 0) v = tv;
  else {
    int k = (j - 1) >> 1;
    float f = (float)(1 << k);
    double arg = 2.0 * PI_D * (double)f * (double)tv;
    v = (j & 1) ? (float)sin(arg) : (float)cos(arg);
  }
  tf[i] = v;
}

// ------------- precompute tconp, zcp, h0, c0 (lane-packed layouts) -------------
__global__ void k_prep(const float* __restrict__ tf, const float* __restrict__ Wih,
                       const float* __restrict__ z,
                       const float* __restrict__ bih, const float* __restrict__ bhh,
                       const float* __restrict__ Whz, const float* __restrict__ bhz,
                       const float* __restrict__ Wcz, const float* __restrict__ bcz,
                       float* tconp, float* zcp, float* h0, float* c0) {
  int i = blockIdx.x * blockDim.x + threadIdx.x;
  if (i < 204800) {
    // tconp[t*1024 + half*512 + u_loc*4 + g]
    int g = i & 3, q = i >> 2;
    int m = q & 127, hm = (q >> 7) & 1, t = q >> 8;
    int n = g * 256 + 128 * hm + m;
    float s = 0.f;
    #pragma unroll
    for (int j = 0; j < 13; ++j) s += tf[t * 13 + j] * Wih[n * 89 + 76 + j];
    tconp[i] = s;
    return;
  }
  i -= 204800;
  if (i < 262144) {
    // zcp[((lbid*512 + tid512)*4 + g)*4 + r] ; tid512 = wv8*64 + ln, unit = 16*wv8 + lr
    int r = i & 3, g = (i >> 2) & 3, tid = (i >> 4) & 511;
    int half = (i >> 13) & 1, pairk = i >> 14;
    int wv = tid >> 6, lr = tid & 15, lq = (tid >> 4) & 3;
    int b = pairk * 16 + lq * 4 + r;
    int n = g * 256 + 128 * half + 16 * wv + lr;
    float s = bih[n] + bhh[n];
    for (int k = 0; k < 64; ++k) s += z[b * 64 + k] * Wih[n * 89 + 12 + k];
    zcp[i] = s;
    return;
  }
  i -= 262144;
  if (i < 65536) {
    int b = i / 256, u = i % 256;
    float s = bhz[u];
    for (int k = 0; k < 64; ++k) s += z[b * 64 + k] * Whz[u * 64 + k];
    h0[i] = s;
    return;
  }
  i -= 65536;
  if (i < 65536) {
    int b = i / 256, u = i % 256;
    float s = bcz[u];
    for (int k = 0; k < 64; ++k) s += z[b * 64 + k] * Wcz[u * 64 + k];
    c0[i] = s;
  }
}

// ------------- bf16 weight casts -------------
__global__ void k_cast(const float* __restrict__ Whh, const float* __restrict__ Wih,
                       const float* __restrict__ Wp1, const float* __restrict__ Wp2,
                       const float* __restrict__ Wo1, const float* __restrict__ Wo2,
                       const float* __restrict__ Wv,
                       bf16* Wcomb, bf16* Wp1b, bf16* Wp2b, bf16* Wo1b,
                       bf16* Wo2b, bf16* Wvb) {
  int i = blockIdx.x * blockDim.x + threadIdx.x;
  if (i < 294912) {
    int n = i / XK, k = i % XK;
    float v = (k < 256) ? Whh[n * 256 + k]
            : ((k < 268) ? Wih[n * 89 + (k - 256)] : 0.f);
    Wcomb[i] = (bf16)v;
    return;
  }
  i -= 294912;
  if (i < 65536) { Wp1b[i] = (bf16)Wp1[i]; return; }
  i -= 65536;
  if (i < 4096) { int r = i / 256; Wp2b[i] = (bf16)((r < 12) ? Wp2[i] : 0.f); return; }
  i -= 4096;
  if (i < 65536) { Wo1b[i] = (bf16)Wo1[i]; return; }
  i -= 65536;
  if (i < 4096) { int r = i / 256; Wo2b[i] = (bf16)((r < 3) ? Wo2[i] : 0.f); return; }
  i -= 4096;
  if (i < 12288) { int r = i / 256; Wvb[i] = (bf16)((r < 42) ? Wv[i] : 0.f); }
}

// ------- recurrent LSTM: 32 blocks (16 pairs x 2 halves), 256 thr, 4 waves -------
// AGPR-resident gate weights (288/lane). Software-pipelined step: gates for
// x_{t+1} are split prev-tile (top of next iter) / own-half (computed under the
// exchange poll) / partner-half (after scatter); p1 likewise split own/partner.
__global__ __launch_bounds__(256, 1) void k_recur(
    const float* __restrict__ zcp, const float* __restrict__ tconp,
    const float* __restrict__ h0, const float* __restrict__ c0,
    const bf16* __restrict__ Wcomb, const bf16* __restrict__ Wp1b,
    const bf16* __restrict__ Wp2b,
    const float* __restrict__ bp1, const float* __restrict__ bp2,
    const float* __restrict__ jlo, const float* __restrict__ jhi,
    const float* __restrict__ ddp,
    u64* hxt,
    bf16* __restrict__ Hseq, float* __restrict__ outJ, float* __restrict__ outA) {
  __shared__ bf16 xbuf[16][XPAD];
  __shared__ bf16 w1[272][P1PAD];      // 0..255 Wp1, 256..271 Wp2
  __shared__ bf16 p1buf[16][P1PAD];
  const int tid = threadIdx.x;
  const int wv = tid >> 6, ln = tid & 63, lr = ln & 15, lq = ln >> 4;
  const int bid = blockIdx.x;
  const int pairk = ((bid >> 4) << 3) | (bid & 7);   // bid^8 shares this (same XCD)
  const int half = (bid >> 3) & 1;
  const int lbid = pairk * 2 + half;
  const int b0 = pairk * 16;

  // ---- one-time LDS fills ----
  for (int i = tid; i < 272 * 32; i += 256) {
    int r = i >> 5, c8 = (i & 31) * 8;
    bf16x8 v = (r < 256)
      ? *reinterpret_cast<const bf16x8*>(&Wp1b[r * 256 + c8])
      : *reinterpret_cast<const bf16x8*>(&Wp2b[(r - 256) * 256 + c8]);
    *reinterpret_cast<bf16x8*>(&w1[r][c8]) = v;
  }
  for (int i = tid; i < 16 * XPAD; i += 256) {
    int r = i / XPAD, c = i % XPAD;
    float v = 0.f;
    if (c < 256) v = h0[(b0 + r) * 256 + c];
    else if (c < 268) {
      int d = c - 256;
      float lo = jlo[d], hi = jhi[d];
      v = (ddp[d] - 0.5f * (hi + lo)) / (0.5f * (hi - lo));
    }
    xbuf[r][c] = (bf16)v;
  }

  // ---- ALL gate weights -> AGPRs (288 regs/lane) ----
  f32x4 wc[2][4][9];
  #pragma unroll
  for (int ji = 0; ji < 2; ++ji) {
    const int ug = 128 * half + 32 * wv + 16 * ji + lr;
    #pragma unroll
    for (int g = 0; g < 4; ++g)
      #pragma unroll
      for (int kt = 0; kt < 9; ++kt)
        wc[ji][g][kt] = *reinterpret_cast<const f32x4*>(
            &Wcomb[(size_t)(g * 256 + ug) * XK + kt * 32 + lq * 8]);
  }
  #pragma unroll
  for (int kt = 0; kt < 9; ++kt)
    asm volatile("" : "+a"(wc[0][0][kt]), "+a"(wc[0][1][kt]),
                      "+a"(wc[0][2][kt]), "+a"(wc[0][3][kt]),
                      "+a"(wc[1][0][kt]), "+a"(wc[1][1][kt]),
                      "+a"(wc[1][2][kt]), "+a"(wc[1][3][kt]));

  // ---- per-lane state ----
  const int ug0 = 128 * half + 32 * wv + lr;
  const int ug1 = ug0 + 16;
  float c_reg[2][4];
  #pragma unroll
  for (int r = 0; r < 4; ++r) {
    c_reg[0][r] = c0[(b0 + lq * 4 + r) * 256 + ug0];
    c_reg[1][r] = c0[(b0 + lq * 4 + r) * 256 + ug1];
  }
  const float* zcb0 = zcp + ((size_t)lbid * 512 + (2 * wv + 0) * 64 + ln) * 16;
  const float* zcb1 = zcp + ((size_t)lbid * 512 + (2 * wv + 1) * 64 + ln) * 16;
  const float* tcb0 = tconp + (size_t)(half * 512 + (32 * wv + lr) * 4);
  const float* tcb1 = tcb0 + 64;
  float bp1r[4];
  #pragma unroll
  for (int jn = 0; jn < 4; ++jn) bp1r[jn] = bp1[64 * wv + 16 * jn + lr];
  float bp2r = 0.f, ddr = 0.f, lor = -1.f, hir = 1.f;
  if (lr < 12) { bp2r = bp2[lr]; ddr = ddp[lr]; lor = jlo[lr]; hir = jhi[lr]; }
  const float jmr = 0.5f * (hir + lor), jrr = 0.5f * (hir - lor);
  bf16* hs0 = Hseq + ((size_t)(b0 + lq * 4) * T_) * 256 + ug0;
  bf16* hs1 = hs0 + 16;

  // ---- exchange bases (slot stride = 2048 u64) ----
  u64* pwb0 = hxt + ((((size_t)(pairk * 2) * 2 + half) * 128 + (32 * wv + lr)) * 4 + lq) * 2;
  u64* pwb1 = hxt + ((((size_t)(pairk * 2) * 2 + half) * 128 + (32 * wv + 16 + lr)) * 4 + lq) * 2;
  const int ru = 32 * wv + (ln >> 1);
  const int rcol = 128 * (half ^ 1) + ru;
  const int row0 = (ln & 1) * 8;
  u64* prb = hxt + ((((size_t)(pairk * 2) * 2 + (half ^ 1)) * 128 + ru) * 4 + 2 * (ln & 1)) * 2;

  const int OH = 4 * half;        // own-half k-tiles
  const int PH = 4 * (half ^ 1);  // partner-half k-tiles

  __syncthreads();

  // ---- prologue: ac = zc + tcon(0) + gates(x_0) over k-tiles 0..7 ----
  f32x4 ac[2][4];
  {
    f32x4 t0 = *reinterpret_cast<const f32x4*>(tcb0);
    f32x4 t1 = *reinterpret_cast<const f32x4*>(tcb1);
    #pragma unroll
    for (int g = 0; g < 4; ++g) {
      ac[0][g] = *reinterpret_cast<const f32x4*>(zcb0 + g * 4) + t0[g];
      ac[1][g] = *reinterpret_cast<const f32x4*>(zcb1 + g * 4) + t1[g];
    }
    #pragma unroll
    for (int kt = 0; kt < 8; ++kt) {
      bf16x8 av = *reinterpret_cast<const bf16x8*>(&xbuf[lr][kt * 32 + lq * 8]);
      #pragma unroll
      for (int ji = 0; ji < 2; ++ji)
        #pragma unroll
        for (int g = 0; g < 4; ++g)
          ac[ji][g] = __builtin_amdgcn_mfma_f32_16x16x32_bf16(
              av, __builtin_bit_cast(bf16x8, wc[ji][g][kt]), ac[ji][g], 0, 0, 0);
    }
  }

  bool dead = false;

  for (int t = 0; t < T_; ++t) {
    // re-pin AGPR weights once per iteration (no fences inside MFMA loops)
    #pragma unroll
    for (int kt = 0; kt < 9; ++kt)
      asm volatile("" : "+a"(wc[0][0][kt]), "+a"(wc[0][1][kt]),
                        "+a"(wc[0][2][kt]), "+a"(wc[0][3][kt]),
                        "+a"(wc[1][0][kt]), "+a"(wc[1][1][kt]),
                        "+a"(wc[1][2][kt]), "+a"(wc[1][3][kt]));

    // ---- (a) finalize gates(x_t): prev-tile kt=8 (cols 256..288) ----
    {
      bf16x8 a8 = *reinterpret_cast<const bf16x8*>(&xbuf[lr][8 * 32 + lq * 8]);
      #pragma unroll
      for (int ji = 0; ji < 2; ++ji)
        #pragma unroll
        for (int g = 0; g < 4; ++g)
          ac[ji][g] = __builtin_amdgcn_mfma_f32_16x16x32_bf16(
              a8, __builtin_bit_cast(bf16x8, wc[ji][g][8]), ac[ji][g], 0, 0, 0);
    }
    // prefetch next-step constants (consumed at (d); latency hidden)
    f32x4 tn0, tn1, zn0[4], zn1[4];
    {
      size_t tp = (size_t)((t + 1 < T_) ? t + 1 : t) * 1024;
      tn0 = *reinterpret_cast<const f32x4*>(tcb0 + tp);
      tn1 = *reinterpret_cast<const f32x4*>(tcb1 + tp);
      #pragma unroll
      for (int g = 0; g < 4; ++g) {
        zn0[g] = *reinterpret_cast<const f32x4*>(zcb0 + g * 4);
        zn1[g] = *reinterpret_cast<const f32x4*>(zcb1 + g * 4);
      }
    }

    // ---- (b) elementwise -> h_{t+1}; publish FIRST; own writes + Hseq ----
    const unsigned int want = t + 1;
    bf16 hb[2][4];
    #pragma unroll
    for (int ji = 0; ji < 2; ++ji) {
      unsigned short s4[4];
      #pragma unroll
      for (int r = 0; r < 4; ++r) {
        float cn = sigf(ac[ji][1][r]) * c_reg[ji][r] + sigf(ac[ji][0][r]) * tanh_f(ac[ji][2][r]);
        float hn = sigf(ac[ji][3][r]) * tanh_f(cn);
        c_reg[ji][r] = cn;
        bf16 h = (bf16)hn;
        hb[ji][r] = h;
        s4[r] = __builtin_bit_cast(unsigned short, h);
      }
      u64 q0 = ((u64)want << 32) | (u64)s4[0] | ((u64)s4[1] << 16);
      u64 q1 = ((u64)want << 32) | (u64)s4[2] | ((u64)s4[3] << 16);
      u64* pw = ((ji == 0) ? pwb0 : pwb1) + (size_t)(t & 1) * 2048;
      __hip_atomic_store(pw, q0, __ATOMIC_RELAXED, __HIP_MEMORY_SCOPE_AGENT);
      __hip_atomic_store(pw + 1, q1, __ATOMIC_RELAXED, __HIP_MEMORY_SCOPE_AGENT);
    }
    #pragma unroll
    for (int r = 0; r < 4; ++r) {
      xbuf[lq * 4 + r][ug0] = hb[0][r];
      xbuf[lq * 4 + r][ug1] = hb[1][r];
      hs0[(size_t)r * (T_ * 256) + (size_t)t * 256] = hb[0][r];
      hs1[(size_t)r * (T_ * 256) + (size_t)t * 256] = hb[1][r];
    }
    LBAR();  // (c) own half of h_{t+1} visible

    // ---- (d) RTT shadow: reinit ac for x_{t+1}; own-half gates + p1 partial ----
    #pragma unroll
    for (int g = 0; g < 4; ++g) { ac[0][g] = zn0[g] + tn0[g]; ac[1][g] = zn1[g] + tn1[g]; }
    f32x4 pp[4];
    #pragma unroll
    for (int jn = 0; jn < 4; ++jn) pp[jn] = (f32x4){bp1r[jn], bp1r[jn], bp1r[jn], bp1r[jn]};
    #pragma unroll
    for (int k = 0; k < 4; ++k) {
      const int kt = OH + k;
      bf16x8 av = *reinterpret_cast<const bf16x8*>(&xbuf[lr][kt * 32 + lq * 8]);
      #pragma unroll
      for (int ji = 0; ji < 2; ++ji)
        #pragma unroll
        for (int g = 0; g < 4; ++g)
          ac[ji][g] = __builtin_amdgcn_mfma_f32_16x16x32_bf16(
              av, __builtin_bit_cast(bf16x8, wc[ji][g][kt]), ac[ji][g], 0, 0, 0);
      #pragma unroll
      for (int jn = 0; jn < 4; ++jn) {
        bf16x8 bv = *reinterpret_cast<const bf16x8*>(&w1[64 * wv + 16 * jn + lr][kt * 32 + lq * 8]);
        pp[jn] = __builtin_amdgcn_mfma_f32_16x16x32_bf16(av, bv, pp[jn], 0, 0, 0);
      }
    }

    // ---- (e) poll partner payload + scatter ----
    {
      u64* pr = prb + (size_t)(t & 1) * 2048;
      u64 pq0, pq1, pq2, pq3;
      int guard = 1 << 16;
      for (;;) {
        pq0 = __hip_atomic_load(pr + 0, __ATOMIC_RELAXED, __HIP_MEMORY_SCOPE_AGENT);
        pq1 = __hip_atomic_load(pr + 1, __ATOMIC_RELAXED, __HIP_MEMORY_SCOPE_AGENT);
        pq2 = __hip_atomic_load(pr + 2, __ATOMIC_RELAXED, __HIP_MEMORY_SCOPE_AGENT);
        pq3 = __hip_atomic_load(pr + 3, __ATOMIC_RELAXED, __HIP_MEMORY_SCOPE_AGENT);
        int ok = ((unsigned)(pq0 >> 32) == want) & ((unsigned)(pq1 >> 32) == want) &
                 ((unsigned)(pq2 >> 32) == want) & ((unsigned)(pq3 >> 32) == want);
        if (__all(ok)) break;
        if (dead || --guard == 0) { dead = true; break; }
      }
      xbuf[row0 + 0][rcol] = __builtin_bit_cast(bf16, (unsigned short)(pq0));
      xbuf[row0 + 1][rcol] = __builtin_bit_cast(bf16, (unsigned short)(pq0 >> 16));
      xbuf[row0 + 2][rcol] = __builtin_bit_cast(bf16, (unsigned short)(pq1));
      xbuf[row0 + 3][rcol] = __builtin_bit_cast(bf16, (unsigned short)(pq1 >> 16));
      xbuf[row0 + 4][rcol] = __builtin_bit_cast(bf16, (unsigned short)(pq2));
      xbuf[row0 + 5][rcol] = __builtin_bit_cast(bf16, (unsigned short)(pq2 >> 16));
      xbuf[row0 + 6][rcol] = __builtin_bit_cast(bf16, (unsigned short)(pq3));
      xbuf[row0 + 7][rcol] = __builtin_bit_cast(bf16, (unsigned short)(pq3 >> 16));
    }
    LBAR();  // (f) full h_{t+1} visible

    // ---- (g) partner-half gates + p1 finish; write p1buf ----
    #pragma unroll
    for (int k = 0; k < 4; ++k) {
      const int kt = PH + k;
      bf16x8 av = *reinterpret_cast<const bf16x8*>(&xbuf[lr][kt * 32 + lq * 8]);
      #pragma unroll
      for (int ji = 0; ji < 2; ++ji)
        #pragma unroll
        for (int g = 0; g < 4; ++g)
          ac[ji][g] = __builtin_amdgcn_mfma_f32_16x16x32_bf16(
              av, __builtin_bit_cast(bf16x8, wc[ji][g][kt]), ac[ji][g], 0, 0, 0);
      #pragma unroll
      for (int jn = 0; jn < 4; ++jn) {
        bf16x8 bv = *reinterpret_cast<const bf16x8*>(&w1[64 * wv + 16 * jn + lr][kt * 32 + lq * 8]);
        pp[jn] = __builtin_amdgcn_mfma_f32_16x16x32_bf16(av, bv, pp[jn], 0, 0, 0);
      }
    }
    #pragma unroll
    for (int jn = 0; jn < 4; ++jn)
      #pragma unroll
      for (int r = 0; r < 4; ++r)
        p1buf[lq * 4 + r][64 * wv + 16 * jn + lr] = (bf16)fmaxf(pp[jn][r], 0.f);
    LBAR();  // (h) p1 visible

    // ---- (i) action head on wave 0 -> outs + prev_norm(t+1) ----
    if (wv == 0) {
      f32x4 acc = {0.f, 0.f, 0.f, 0.f};
      #pragma unroll
      for (int kt = 0; kt < 8; ++kt) {
        bf16x8 ap = *reinterpret_cast<const bf16x8*>(&p1buf[lr][kt * 32 + lq * 8]);
        bf16x8 w2 = *reinterpret_cast<const bf16x8*>(&w1[256 + lr][kt * 32 + lq * 8]);
        acc = __builtin_amdgcn_mfma_f32_16x16x32_bf16(ap, w2, acc, 0, 0, 0);
      }
      if (lr < 12) {
        #pragma unroll
        for (int r = 0; r < 4; ++r) {
          int b = lq * 4 + r;
          float act = tanh_f(acc[r] + bp2r);
          float curp = act * 0.25f + ddr;   // TRACK_ALPHA = 1
          float cl = fminf(fmaxf(curp, lor), hir);
          if (half == 0) {
            size_t o = ((size_t)(b0 + b) * T_ + t) * 12 + lr;
            outA[o] = act;
            outJ[o] = curp;
          }
          xbuf[b][256 + lr] = (bf16)((cl - jmr) / jrr);
        }
      }
    }
    LBAR();  // (j) prev_norm visible for next iteration's prev-tile
  }
}

// ------------- post pass: obj head, sigma head, FK, normalize -------------
__global__ __launch_bounds__(256) void k_post(
    const bf16* __restrict__ Hseq, const bf16* __restrict__ Wo1b,
    const bf16* __restrict__ Wo2b, const bf16* __restrict__ Wvb,
    const float* __restrict__ bo1, const float* __restrict__ bo2,
    const float* __restrict__ bv,
    const float* __restrict__ Wfk, const float* __restrict__ bfk,
    const float* __restrict__ pm, const float* __restrict__ ps,
    const float* __restrict__ joints, float* __restrict__ out0,
    float* __restrict__ out3) {
  __shared__ bf16 u1buf[16][P1PAD];
  __shared__ float objbuf[16][3];
  __shared__ float jbuf[16][12];
  const int tid = threadIdx.x;
  const int wv = tid >> 6;
  const int ln = tid & 63;
  const int lr = ln & 15;
  const int lq = ln >> 4;

  bf16x8 wo1f[4][8];
  float bo1r[4];
  #pragma unroll
  for (int jn = 0; jn < 4; ++jn) {
    int n0 = wv * 64 + jn * 16;
    bo1r[jn] = bo1[n0 + lr];
    #pragma unroll
    for (int kt = 0; kt < 8; ++kt)
      wo1f[jn][kt] = *reinterpret_cast<const bf16x8*>(
          &Wo1b[(size_t)(n0 + lr) * 256 + kt * 32 + lq * 8]);
  }
  const int col = (wv - 1) * 16 + lr;
  bf16x8 wvf[8];
  float bvr = 0.f;
  if (wv >= 1) {
    #pragma unroll
    for (int kt = 0; kt < 8; ++kt)
      wvf[kt] = *reinterpret_cast<const bf16x8*>(
          &Wvb[(size_t)col * 256 + kt * 32 + lq * 8]);
    bvr = (col < 42) ? bv[col] : 0.f;
  }
  bf16x8 wo2f[8];
  if (wv == 0) {
    #pragma unroll
    for (int kt = 0; kt < 8; ++kt)
      wo2f[kt] = *reinterpret_cast<const bf16x8*>(
          &Wo2b[(size_t)lr * 256 + kt * 32 + lq * 8]);
  }

  for (int it = 0; it < 10; ++it) {
    int tt = blockIdx.x * 10 + it;
    size_t r0 = (size_t)tt * 16;
    bf16x8 ah[8];
    #pragma unroll
    for (int kt = 0; kt < 8; ++kt)
      ah[kt] = *reinterpret_cast<const bf16x8*>(&Hseq[(r0 + lr) * 256 + kt * 32 + lq * 8]);
    #pragma unroll
    for (int jn = 0; jn < 4; ++jn) {
      int n0 = wv * 64 + jn * 16;
      float bb = bo1r[jn];
      f32x4 acc = {bb, bb, bb, bb};
      #pragma unroll
      for (int kt = 0; kt < 8; ++kt)
        acc = __builtin_amdgcn_mfma_f32_16x16x32_bf16(ah[kt], wo1f[jn][kt], acc, 0, 0, 0);
      #pragma unroll
      for (int r = 0; r < 4; ++r)
        u1buf[lq * 4 + r][n0 + lr] = (bf16)fmaxf(acc[r], 0.f);
    }
    if (wv >= 1) {
      f32x4 acc = {bvr, bvr, bvr, bvr};
      #pragma unroll
      for (int kt = 0; kt < 8; ++kt)
        acc = __builtin_amdgcn_mfma_f32_16x16x32_bf16(ah[kt], wvf[kt], acc, 0, 0, 0);
      if (col < 42) {
        #pragma unroll
        for (int r = 0; r < 4; ++r) {
          float s = 0.05f + 0.45f * sigf(acc[r]);
          out3[(r0 + lq * 4 + r) * 42 + col] = __logf(s);
        }
      }
    }
    if (tid < 192) {
      int rr = tid / 12, d = tid % 12;
      jbuf[rr][d] = joints[(r0 + rr) * 12 + d];
    }
    __syncthreads();
    if (wv == 0) {
      bf16x8 ap[8];
      #pragma unroll
      for (int kt = 0; kt < 8; ++kt)
        ap[kt] = *reinterpret_cast<const bf16x8*>(&u1buf[lr][kt * 32 + lq * 8]);
      f32x4 acc = {0.f, 0.f, 0.f, 0.f};
      #pragma unroll
      for (int kt = 0; kt < 8; ++kt)
        acc = __builtin_amdgcn_mfma_f32_16x16x32_bf16(ap[kt], wo2f[kt], acc, 0, 0, 0);
      if (lr < 3) {
        #pragma unroll
        for (int r = 0; r < 4; ++r)
          objbuf[lq * 4 + r][lr] = acc[r] + bo2[lr];
      }
    }
    __syncthreads();
    for (int e = tid; e < 16 * 42; e += 256) {
      int rr = e / 42, pd = e % 42;
      float v;
      if (pd < 39) {
        float s = bfk[pd];
        #pragma unroll
        for (int d = 0; d < 12; ++d) s += jbuf[rr][d] * Wfk[pd * 12 + d];
        v = s;
      } else v = objbuf[rr][pd - 39];
      out0[(r0 + rr) * 42 + pd] = (v - pm[pd]) / ps[pd];
    }
    __syncthreads();
  }
}

extern "C" void kernel_launch(void* const* d_in, const int* in_sizes, int n_in,
                              void* d_out, int out_size, void* d_ws, size_t ws_size,
                              hipStream_t stream) {
  const float* z   = (const float*)d_in[0];
  const float* Whz = (const float*)d_in[1];
  const float* bhz = (const float*)d_in[2];
  const float* Wcz = (const float*)d_in[3];
  const float* bcz = (const float*)d_in[4];
  const float* Wih = (const float*)d_in[5];
  const float* Whh = (const float*)d_in[6];
  const float* bih = (const float*)d_in[7];
  const float* bhh = (const float*)d_in[8];
  const float* Wp1 = (const float*)d_in[9];
  const float* bp1 = (const float*)d_in[10];
  const float* Wp2 = (const float*)d_in[11];
  const float* bp2 = (const float*)d_in[12];
  const float* Wo1 = (const float*)d_in[13];
  const float* bo1 = (const float*)d_in[14];
  const float* Wo2 = (const float*)d_in[15];
  const float* bo2 = (const float*)d_in[16];
  const float* Wv  = (const float*)d_in[17];
  const float* bv  = (const float*)d_in[18];
  const float* Wfk = (const float*)d_in[19];
  const float* bfk = (const float*)d_in[20];
  const float* pm  = (const float*)d_in[21];
  const float* ps  = (const float*)d_in[22];
  const float* jlo = (const float*)d_in[23];
  const float* jhi = (const float*)d_in[24];
  const float* ddp = (const float*)d_in[25];

  char* ws = (char*)d_ws;
  float* tf    = (float*)(ws + OFF_TF);
  float* tconp = (float*)(ws + OFF_TCONP);
  float* zcp   = (float*)(ws + OFF_ZCP);
  float* h0    = (float*)(ws + OFF_H0);
  float* c0    = (float*)(ws + OFF_C0);
  bf16* Wcomb  = (bf16*)(ws + OFF_WCOMB);
  bf16* Wp1b   = (bf16*)(ws + OFF_WP1);
  bf16* Wp2b   = (bf16*)(ws + OFF_WP2);
  bf16* Wo1b   = (bf16*)(ws + OFF_WO1);
  bf16* Wo2b   = (bf16*)(ws + OFF_WO2);
  bf16* Wvb    = (bf16*)(ws + OFF_WV);
  u64* hxt     = (u64*)(ws + OFF_HX);
  bf16* Hseq   = (bf16*)(ws + OFF_HSEQ);

  float* out  = (float*)d_out;
  float* out0 = out;                 // graph_x_mu [B,T,42]
  float* outJ = out + 2150400;       // joint_traj [B,T,12]
  float* outA = out + 2764800;       // actions    [B,T,12]
  float* out3 = out + 3379200;       // log_sigma  [B,T,42]

  k_tfeat<<<11, 256, 0, stream>>>(tf);
  k_prep<<<2336, 256, 0, stream>>>(tf, Wih, z, bih, bhh, Whz, bhz, Wcz, bcz,
                                   tconp, zcp, h0, c0);
  k_cast<<<1744, 256, 0, stream>>>(Whh, Wih, Wp1, Wp2, Wo1, Wo2, Wv,
                                   Wcomb, Wp1b, Wp2b, Wo1b, Wo2b, Wvb);
  k_recur<<<32, 256, 0, stream>>>(zcp, tconp, h0, c0, Wcomb, Wp1b, Wp2b,
                                  bp1, bp2, jlo, jhi, ddp, hxt,
                                  Hseq, outJ, outA);
  k_post<<<320, 256, 0, stream>>>(Hseq, Wo1b, Wo2b, Wvb, bo1, bo2, bv,
                                  Wfk, bfk, pm, ps, outJ, out0, out3);
}

// Round 12
// 1094.037 us; speedup vs baseline: 4.5401x; 4.5401x over previous
//
#include <hip/hip_runtime.h>
#include <math.h>

#define B_ 256
#define T_ 200
#define H_ 256
#define DOF_ 12

typedef __bf16 bf16;
typedef __bf16 bf16x8 __attribute__((ext_vector_type(8)));
typedef float f32x4 __attribute__((ext_vector_type(4)));
typedef unsigned long long u64;

#define XK 288      // gate GEMM K: 256 h + 12 prev + 20 zero pad
#define XPAD 296
#define P1PAD 264

#define PI_D 3.14159265358979323846

// ---- workspace byte offsets (all 16B aligned) ----
#define OFF_TF     0u
#define OFF_TCONP  10400u
#define OFF_ZCP    829600u
#define OFF_H0     1878176u
#define OFF_C0     2140320u
#define OFF_WCOMB  2402464u
#define OFF_WP1    2992288u
#define OFF_WP2    3123360u
#define OFF_WO1    3131552u
#define OFF_WO2    3262624u
#define OFF_WV     3270816u
#define OFF_HX     3295392u    // 16 pairs * 2 slots * 2 halves * 128 * 4 * 16B = 512KB
#define OFF_HSEQ   3819680u    // 256*200*256*2 = 26214400 (end ~30.0MB)

__device__ __forceinline__ float sigf(float x) { return 1.f / (1.f + __expf(-x)); }
__device__ __forceinline__ float tanh_f(float x) {
  float a = fabsf(x);
  float e = __expf(-2.f * a);
  float t = (1.f - e) * __builtin_amdgcn_rcpf(1.f + e);
  return x < 0.f ? -t : t;
}

// light barrier: order LDS, leave global ops in flight
#define LBAR() asm volatile("s_waitcnt lgkmcnt(0)\n\ts_barrier" ::: "memory")

// ---------------- time features [T,13] ----------------
__global__ void k_tfeat(float* tf) {
  int i = blockIdx.x * blockDim.x + threadIdx.x;
  if (i >= T_ * 13) return;
  int t = i / 13, j = i % 13;
  float tv = (float)t / 199.f;
  float v;
  if (j == 0) v = tv;
  else {
    int k = (j - 1) >> 1;
    float f = (float)(1 << k);
    double arg = 2.0 * PI_D * (double)f * (double)tv;
    v = (j & 1) ? (float)sin(arg) : (float)cos(arg);
  }
  tf[i] = v;
}

// ------------- precompute tconp, zcp, h0, c0 (lane-packed layouts) -------------
__global__ void k_prep(const float* __restrict__ tf, const float* __restrict__ Wih,
                       const float* __restrict__ z,
                       const float* __restrict__ bih, const float* __restrict__ bhh,
                       const float* __restrict__ Whz, const float* __restrict__ bhz,
                       const float* __restrict__ Wcz, const float* __restrict__ bcz,
                       float* tconp, float* zcp, float* h0, float* c0) {
  int i = blockIdx.x * blockDim.x + threadIdx.x;
  if (i < 204800) {
    // tconp[t*1024 + half*512 + u_loc*4 + g]
    int g = i & 3, q = i >> 2;
    int m = q & 127, hm = (q >> 7) & 1, t = q >> 8;
    int n = g * 256 + 128 * hm + m;
    float s = 0.f;
    #pragma unroll
    for (int j = 0; j < 13; ++j) s += tf[t * 13 + j] * Wih[n * 89 + 76 + j];
    tconp[i] = s;
    return;
  }
  i -= 204800;
  if (i < 262144) {
    // zcp[((lbid*512 + tid512)*4 + g)*4 + r] ; tid512 = wv8*64 + ln, unit = 16*wv8 + lr
    int r = i & 3, g = (i >> 2) & 3, tid = (i >> 4) & 511;
    int half = (i >> 13) & 1, pairk = i >> 14;
    int wv = tid >> 6, lr = tid & 15, lq = (tid >> 4) & 3;
    int b = pairk * 16 + lq * 4 + r;
    int n = g * 256 + 128 * half + 16 * wv + lr;
    float s = bih[n] + bhh[n];
    for (int k = 0; k < 64; ++k) s += z[b * 64 + k] * Wih[n * 89 + 12 + k];
    zcp[i] = s;
    return;
  }
  i -= 262144;
  if (i < 65536) {
    int b = i / 256, u = i % 256;
    float s = bhz[u];
    for (int k = 0; k < 64; ++k) s += z[b * 64 + k] * Whz[u * 64 + k];
    h0[i] = s;
    return;
  }
  i -= 65536;
  if (i < 65536) {
    int b = i / 256, u = i % 256;
    float s = bcz[u];
    for (int k = 0; k < 64; ++k) s += z[b * 64 + k] * Wcz[u * 64 + k];
    c0[i] = s;
  }
}

// ------------- bf16 weight casts -------------
__global__ void k_cast(const float* __restrict__ Whh, const float* __restrict__ Wih,
                       const float* __restrict__ Wp1, const float* __restrict__ Wp2,
                       const float* __restrict__ Wo1, const float* __restrict__ Wo2,
                       const float* __restrict__ Wv,
                       bf16* Wcomb, bf16* Wp1b, bf16* Wp2b, bf16* Wo1b,
                       bf16* Wo2b, bf16* Wvb) {
  int i = blockIdx.x * blockDim.x + threadIdx.x;
  if (i < 294912) {
    int n = i / XK, k = i % XK;
    float v = (k < 256) ? Whh[n * 256 + k]
            : ((k < 268) ? Wih[n * 89 + (k - 256)] : 0.f);
    Wcomb[i] = (bf16)v;
    return;
  }
  i -= 294912;
  if (i < 65536) { Wp1b[i] = (bf16)Wp1[i]; return; }
  i -= 65536;
  if (i < 4096) { int r = i / 256; Wp2b[i] = (bf16)((r < 12) ? Wp2[i] : 0.f); return; }
  i -= 4096;
  if (i < 65536) { Wo1b[i] = (bf16)Wo1[i]; return; }
  i -= 65536;
  if (i < 4096) { int r = i / 256; Wo2b[i] = (bf16)((r < 3) ? Wo2[i] : 0.f); return; }
  i -= 4096;
  if (i < 12288) { int r = i / 256; Wvb[i] = (bf16)((r < 42) ? Wv[i] : 0.f); }
}

// ------- recurrent LSTM: 32 blocks (16 pairs x 2 halves), 256 thr, 4 waves -------
// 1 wave/SIMD -> 512-reg budget/wave: ALL 4 gates' weights (288 regs) pinned in
// AGPRs; zc NOT resident (per-step L2 reload hidden under gates) so arch VGPRs
// + AGPRs fit the 512 budget spill-free. Wp1+Wp2 in LDS. Tag-embedded u64
// relaxed agent-atomic exchange of h halves, batched 4-load poll.
__global__ __launch_bounds__(256, 1) void k_recur(
    const float* __restrict__ zcp, const float* __restrict__ tconp,
    const float* __restrict__ h0, const float* __restrict__ c0,
    const bf16* __restrict__ Wcomb, const bf16* __restrict__ Wp1b,
    const bf16* __restrict__ Wp2b,
    const float* __restrict__ bp1, const float* __restrict__ bp2,
    const float* __restrict__ jlo, const float* __restrict__ jhi,
    const float* __restrict__ ddp,
    u64* hxt,
    bf16* __restrict__ Hseq, float* __restrict__ outJ, float* __restrict__ outA) {
  __shared__ bf16 xbuf[16][XPAD];
  __shared__ bf16 w1[272][P1PAD];      // 0..255 Wp1, 256..271 Wp2
  __shared__ bf16 p1buf[16][P1PAD];
  const int tid = threadIdx.x;
  const int wv = tid >> 6, ln = tid & 63, lr = ln & 15, lq = ln >> 4;
  const int bid = blockIdx.x;
  const int pairk = ((bid >> 4) << 3) | (bid & 7);   // bid^8 shares this (same XCD)
  const int half = (bid >> 3) & 1;
  const int lbid = pairk * 2 + half;
  const int b0 = pairk * 16;

  // ---- one-time LDS fills (stride 256) ----
  for (int i = tid; i < 272 * 32; i += 256) {
    int r = i >> 5, c8 = (i & 31) * 8;
    bf16x8 v = (r < 256)
      ? *reinterpret_cast<const bf16x8*>(&Wp1b[r * 256 + c8])
      : *reinterpret_cast<const bf16x8*>(&Wp2b[(r - 256) * 256 + c8]);
    *reinterpret_cast<bf16x8*>(&w1[r][c8]) = v;
  }
  for (int i = tid; i < 16 * XPAD; i += 256) {
    int r = i / XPAD, c = i % XPAD;
    float v = 0.f;
    if (c < 256) v = h0[(b0 + r) * 256 + c];
    else if (c < 268) {
      int d = c - 256;
      float lo = jlo[d], hi = jhi[d];
      v = (ddp[d] - 0.5f * (hi + lo)) / (0.5f * (hi - lo));
    }
    xbuf[r][c] = (bf16)v;
  }

  // ---- ALL gate weights -> AGPRs (288 regs/lane) ----
  // wave owns units u_loc = 32*wv + 16*ji + lr, ji in {0,1}
  f32x4 wc[2][4][9];
  #pragma unroll
  for (int ji = 0; ji < 2; ++ji) {
    const int ug = 128 * half + 32 * wv + 16 * ji + lr;
    #pragma unroll
    for (int g = 0; g < 4; ++g)
      #pragma unroll
      for (int kt = 0; kt < 9; ++kt)
        wc[ji][g][kt] = *reinterpret_cast<const f32x4*>(
            &Wcomb[(size_t)(g * 256 + ug) * XK + kt * 32 + lq * 8]);
  }
  #pragma unroll
  for (int kt = 0; kt < 9; ++kt)
    asm volatile("" : "+a"(wc[0][0][kt]), "+a"(wc[0][1][kt]),
                      "+a"(wc[0][2][kt]), "+a"(wc[0][3][kt]),
                      "+a"(wc[1][0][kt]), "+a"(wc[1][1][kt]),
                      "+a"(wc[1][2][kt]), "+a"(wc[1][3][kt]));

  // ---- per-lane state (zc NOT resident: reloaded per step, hidden) ----
  float c_reg[2][4];
  bf16* hs[2];
  const int ug0c = 128 * half + 32 * wv + lr;
  #pragma unroll
  for (int ji = 0; ji < 2; ++ji) {
    const int ug = ug0c + 16 * ji;
    #pragma unroll
    for (int r = 0; r < 4; ++r) c_reg[ji][r] = c0[(b0 + lq * 4 + r) * 256 + ug];
    hs[ji] = Hseq + ((size_t)(b0 + lq * 4) * T_) * 256 + ug;
  }
  const float* zcb0 = zcp + ((size_t)lbid * 512 + (2 * wv + 0) * 64 + ln) * 16;
  const float* zcb1 = zcp + ((size_t)lbid * 512 + (2 * wv + 1) * 64 + ln) * 16;
  const float* tcb0 = tconp + (size_t)(half * 512 + (32 * wv + lr) * 4);
  const float* tcb1 = tcb0 + 64;   // +16 units * 4
  // p1: wave owns 64 cols [64wv, 64wv+64)
  float bp1r[4];
  #pragma unroll
  for (int jn = 0; jn < 4; ++jn) bp1r[jn] = bp1[64 * wv + 16 * jn + lr];
  float bp2r = 0.f, ddr = 0.f, lor = -1.f, hir = 1.f;
  if (lr < 12) { bp2r = bp2[lr]; ddr = ddp[lr]; lor = jlo[lr]; hir = jhi[lr]; }
  const float jmr = 0.5f * (hir + lor), jrr = 0.5f * (hir - lor);

  // ---- exchange addresses ----
  u64* pws[2][2];
  #pragma unroll
  for (int ji = 0; ji < 2; ++ji) {
    const int ul = 32 * wv + 16 * ji + lr;
    #pragma unroll
    for (int s = 0; s < 2; ++s)
      pws[ji][s] = hxt + ((((size_t)(pairk * 2 + s) * 2 + half) * 128 + ul) * 4 + lq) * 2;
  }
  const int ru = 32 * wv + (ln >> 1);
  const int rcol = 128 * (half ^ 1) + ru;
  const int row0 = (ln & 1) * 8;
  u64* prs[2];
  #pragma unroll
  for (int s = 0; s < 2; ++s)
    prs[s] = hxt + ((((size_t)(pairk * 2 + s) * 2 + (half ^ 1)) * 128 + ru) * 4 + 2 * (ln & 1)) * 2;

  f32x4 tcv0 = *reinterpret_cast<const f32x4*>(tcb0);
  f32x4 tcv1 = *reinterpret_cast<const f32x4*>(tcb1);
  __syncthreads();
  bool dead = false;

  for (int t = 0; t < T_; ++t) {
    // ---- issue zc loads early (L2-resident; hidden under the 72-MFMA loop) ----
    f32x4 zc0[4], zc1[4];
    #pragma unroll
    for (int g = 0; g < 4; ++g) {
      zc0[g] = *reinterpret_cast<const f32x4*>(zcb0 + g * 4);
      zc1[g] = *reinterpret_cast<const f32x4*>(zcb1 + g * 4);
    }
    // ---- gates: kt-outer, shared A fragment, AGPR weights, zero-init C ----
    f32x4 ac[2][4];
    #pragma unroll
    for (int ji = 0; ji < 2; ++ji)
      #pragma unroll
      for (int g = 0; g < 4; ++g) ac[ji][g] = (f32x4){0.f, 0.f, 0.f, 0.f};
    #pragma unroll
    for (int kt = 0; kt < 9; ++kt) {
      bf16x8 a = *reinterpret_cast<const bf16x8*>(&xbuf[lr][kt * 32 + lq * 8]);
      asm volatile("" : "+a"(wc[0][0][kt]), "+a"(wc[0][1][kt]),
                        "+a"(wc[0][2][kt]), "+a"(wc[0][3][kt]),
                        "+a"(wc[1][0][kt]), "+a"(wc[1][1][kt]),
                        "+a"(wc[1][2][kt]), "+a"(wc[1][3][kt]));
      #pragma unroll
      for (int ji = 0; ji < 2; ++ji)
        #pragma unroll
        for (int g = 0; g < 4; ++g)
          ac[ji][g] = __builtin_amdgcn_mfma_f32_16x16x32_bf16(
              a, __builtin_bit_cast(bf16x8, wc[ji][g][kt]), ac[ji][g], 0, 0, 0);
    }
    // fold biases in now (zc loads have long since landed)
    #pragma unroll
    for (int g = 0; g < 4; ++g) {
      ac[0][g] += zc0[g] + tcv0[g];
      ac[1][g] += zc1[g] + tcv1[g];
    }
    LBAR();  // all xbuf reads done before h overwrite

    // ---- LSTM elementwise + publish (tag-embedded) ----
    const unsigned int want = t + 1;
    bf16 hb[2][4];
    #pragma unroll
    for (int ji = 0; ji < 2; ++ji) {
      unsigned short s4[4];
      #pragma unroll
      for (int r = 0; r < 4; ++r) {
        float cn = sigf(ac[ji][1][r]) * c_reg[ji][r] + sigf(ac[ji][0][r]) * tanh_f(ac[ji][2][r]);
        float hn = sigf(ac[ji][3][r]) * tanh_f(cn);
        c_reg[ji][r] = cn;
        bf16 h = (bf16)hn;
        hb[ji][r] = h;
        s4[r] = __builtin_bit_cast(unsigned short, h);
      }
      u64 q0 = ((u64)want << 32) | (u64)s4[0] | ((u64)s4[1] << 16);
      u64 q1 = ((u64)want << 32) | (u64)s4[2] | ((u64)s4[3] << 16);
      u64* pw = pws[ji][t & 1];
      __hip_atomic_store(pw, q0, __ATOMIC_RELAXED, __HIP_MEMORY_SCOPE_AGENT);
      __hip_atomic_store(pw + 1, q1, __ATOMIC_RELAXED, __HIP_MEMORY_SCOPE_AGENT);
    }
    // own h -> xbuf + Hseq; next-step tcon prefetch (all in the poll shadow)
    #pragma unroll
    for (int ji = 0; ji < 2; ++ji) {
      const int ug = ug0c + 16 * ji;
      #pragma unroll
      for (int r = 0; r < 4; ++r) {
        xbuf[lq * 4 + r][ug] = hb[ji][r];
        hs[ji][(size_t)r * (T_ * 256) + (size_t)t * 256] = hb[ji][r];
      }
    }
    {
      size_t tp = (size_t)((t + 1 < T_) ? t + 1 : t) * 1024;
      f32x4 tn0 = *reinterpret_cast<const f32x4*>(tcb0 + tp);
      f32x4 tn1 = *reinterpret_cast<const f32x4*>(tcb1 + tp);
      tcv0 = tn0; tcv1 = tn1;
    }

    // ---- batched poll: 4 u64 per lane, one waitcnt per attempt ----
    u64 pq0, pq1, pq2, pq3;
    {
      u64* pr = prs[t & 1];
      int guard = 1 << 16;
      for (;;) {
        pq0 = __hip_atomic_load(pr + 0, __ATOMIC_RELAXED, __HIP_MEMORY_SCOPE_AGENT);
        pq1 = __hip_atomic_load(pr + 1, __ATOMIC_RELAXED, __HIP_MEMORY_SCOPE_AGENT);
        pq2 = __hip_atomic_load(pr + 2, __ATOMIC_RELAXED, __HIP_MEMORY_SCOPE_AGENT);
        pq3 = __hip_atomic_load(pr + 3, __ATOMIC_RELAXED, __HIP_MEMORY_SCOPE_AGENT);
        int ok = ((unsigned)(pq0 >> 32) == want) & ((unsigned)(pq1 >> 32) == want) &
                 ((unsigned)(pq2 >> 32) == want) & ((unsigned)(pq3 >> 32) == want);
        if (__all(ok)) break;
        if (dead || --guard == 0) { dead = true; break; }
      }
    }
    xbuf[row0 + 0][rcol] = __builtin_bit_cast(bf16, (unsigned short)(pq0));
    xbuf[row0 + 1][rcol] = __builtin_bit_cast(bf16, (unsigned short)(pq0 >> 16));
    xbuf[row0 + 2][rcol] = __builtin_bit_cast(bf16, (unsigned short)(pq1));
    xbuf[row0 + 3][rcol] = __builtin_bit_cast(bf16, (unsigned short)(pq1 >> 16));
    xbuf[row0 + 4][rcol] = __builtin_bit_cast(bf16, (unsigned short)(pq2));
    xbuf[row0 + 5][rcol] = __builtin_bit_cast(bf16, (unsigned short)(pq2 >> 16));
    xbuf[row0 + 6][rcol] = __builtin_bit_cast(bf16, (unsigned short)(pq3));
    xbuf[row0 + 7][rcol] = __builtin_bit_cast(bf16, (unsigned short)(pq3 >> 16));
    LBAR();  // full h_new visible

    // ---- p1 = relu(h_new @ Wp1^T + bp1): wave owns 64 cols, kt-outer ----
    {
      f32x4 pa0 = {bp1r[0], bp1r[0], bp1r[0], bp1r[0]};
      f32x4 pa1 = {bp1r[1], bp1r[1], bp1r[1], bp1r[1]};
      f32x4 pa2 = {bp1r[2], bp1r[2], bp1r[2], bp1r[2]};
      f32x4 pa3 = {bp1r[3], bp1r[3], bp1r[3], bp1r[3]};
      #pragma unroll
      for (int kt = 0; kt < 8; ++kt) {
        bf16x8 av = *reinterpret_cast<const bf16x8*>(&xbuf[lr][kt * 32 + lq * 8]);
        bf16x8 b0v = *reinterpret_cast<const bf16x8*>(&w1[64 * wv + lr][kt * 32 + lq * 8]);
        bf16x8 b1v = *reinterpret_cast<const bf16x8*>(&w1[64 * wv + 16 + lr][kt * 32 + lq * 8]);
        bf16x8 b2v = *reinterpret_cast<const bf16x8*>(&w1[64 * wv + 32 + lr][kt * 32 + lq * 8]);
        bf16x8 b3v = *reinterpret_cast<const bf16x8*>(&w1[64 * wv + 48 + lr][kt * 32 + lq * 8]);
        pa0 = __builtin_amdgcn_mfma_f32_16x16x32_bf16(av, b0v, pa0, 0, 0, 0);
        pa1 = __builtin_amdgcn_mfma_f32_16x16x32_bf16(av, b1v, pa1, 0, 0, 0);
        pa2 = __builtin_amdgcn_mfma_f32_16x16x32_bf16(av, b2v, pa2, 0, 0, 0);
        pa3 = __builtin_amdgcn_mfma_f32_16x16x32_bf16(av, b3v, pa3, 0, 0, 0);
      }
      #pragma unroll
      for (int r = 0; r < 4; ++r) {
        p1buf[lq * 4 + r][64 * wv + lr]      = (bf16)fmaxf(pa0[r], 0.f);
        p1buf[lq * 4 + r][64 * wv + 16 + lr] = (bf16)fmaxf(pa1[r], 0.f);
        p1buf[lq * 4 + r][64 * wv + 32 + lr] = (bf16)fmaxf(pa2[r], 0.f);
        p1buf[lq * 4 + r][64 * wv + 48 + lr] = (bf16)fmaxf(pa3[r], 0.f);
      }
    }
    LBAR();  // p1 visible

    // ---- action head on wave 0 (redundant across halves; writes gated) ----
    if (wv == 0) {
      f32x4 acc = {0.f, 0.f, 0.f, 0.f};
      #pragma unroll
      for (int kt = 0; kt < 8; ++kt) {
        bf16x8 ap = *reinterpret_cast<const bf16x8*>(&p1buf[lr][kt * 32 + lq * 8]);
        bf16x8 w2 = *reinterpret_cast<const bf16x8*>(&w1[256 + lr][kt * 32 + lq * 8]);
        acc = __builtin_amdgcn_mfma_f32_16x16x32_bf16(ap, w2, acc, 0, 0, 0);
      }
      if (lr < 12) {
        #pragma unroll
        for (int r = 0; r < 4; ++r) {
          int b = lq * 4 + r;
          float act = tanh_f(acc[r] + bp2r);
          float curp = act * 0.25f + ddr;   // TRACK_ALPHA = 1
          float cl = fminf(fmaxf(curp, lor), hir);
          if (half == 0) {
            size_t o = ((size_t)(b0 + b) * T_ + t) * 12 + lr;
            outA[o] = act;
            outJ[o] = curp;
          }
          xbuf[b][256 + lr] = (bf16)((cl - jmr) / jrr);
        }
      }
    }
    LBAR();  // prev_norm visible for next step
  }
}

// ------------- post pass: obj head, sigma head, FK, normalize -------------
__global__ __launch_bounds__(256) void k_post(
    const bf16* __restrict__ Hseq, const bf16* __restrict__ Wo1b,
    const bf16* __restrict__ Wo2b, const bf16* __restrict__ Wvb,
    const float* __restrict__ bo1, const float* __restrict__ bo2,
    const float* __restrict__ bv,
    const float* __restrict__ Wfk, const float* __restrict__ bfk,
    const float* __restrict__ pm, const float* __restrict__ ps,
    const float* __restrict__ joints, float* __restrict__ out0,
    float* __restrict__ out3) {
  __shared__ bf16 u1buf[16][P1PAD];
  __shared__ float objbuf[16][3];
  __shared__ float jbuf[16][12];
  const int tid = threadIdx.x;
  const int wv = tid >> 6;
  const int ln = tid & 63;
  const int lr = ln & 15;
  const int lq = ln >> 4;

  bf16x8 wo1f[4][8];
  float bo1r[4];
  #pragma unroll
  for (int jn = 0; jn < 4; ++jn) {
    int n0 = wv * 64 + jn * 16;
    bo1r[jn] = bo1[n0 + lr];
    #pragma unroll
    for (int kt = 0; kt < 8; ++kt)
      wo1f[jn][kt] = *reinterpret_cast<const bf16x8*>(
          &Wo1b[(size_t)(n0 + lr) * 256 + kt * 32 + lq * 8]);
  }
  const int col = (wv - 1) * 16 + lr;
  bf16x8 wvf[8];
  float bvr = 0.f;
  if (wv >= 1) {
    #pragma unroll
    for (int kt = 0; kt < 8; ++kt)
      wvf[kt] = *reinterpret_cast<const bf16x8*>(
          &Wvb[(size_t)col * 256 + kt * 32 + lq * 8]);
    bvr = (col < 42) ? bv[col] : 0.f;
  }
  bf16x8 wo2f[8];
  if (wv == 0) {
    #pragma unroll
    for (int kt = 0; kt < 8; ++kt)
      wo2f[kt] = *reinterpret_cast<const bf16x8*>(
          &Wo2b[(size_t)lr * 256 + kt * 32 + lq * 8]);
  }

  for (int it = 0; it < 10; ++it) {
    int tt = blockIdx.x * 10 + it;
    size_t r0 = (size_t)tt * 16;
    bf16x8 ah[8];
    #pragma unroll
    for (int kt = 0; kt < 8; ++kt)
      ah[kt] = *reinterpret_cast<const bf16x8*>(&Hseq[(r0 + lr) * 256 + kt * 32 + lq * 8]);
    #pragma unroll
    for (int jn = 0; jn < 4; ++jn) {
      int n0 = wv * 64 + jn * 16;
      float bb = bo1r[jn];
      f32x4 acc = {bb, bb, bb, bb};
      #pragma unroll
      for (int kt = 0; kt < 8; ++kt)
        acc = __builtin_amdgcn_mfma_f32_16x16x32_bf16(ah[kt], wo1f[jn][kt], acc, 0, 0, 0);
      #pragma unroll
      for (int r = 0; r < 4; ++r)
        u1buf[lq * 4 + r][n0 + lr] = (bf16)fmaxf(acc[r], 0.f);
    }
    if (wv >= 1) {
      f32x4 acc = {bvr, bvr, bvr, bvr};
      #pragma unroll
      for (int kt = 0; kt < 8; ++kt)
        acc = __builtin_amdgcn_mfma_f32_16x16x32_bf16(ah[kt], wvf[kt], acc, 0, 0, 0);
      if (col < 42) {
        #pragma unroll
        for (int r = 0; r < 4; ++r) {
          float s = 0.05f + 0.45f * sigf(acc[r]);
          out3[(r0 + lq * 4 + r) * 42 + col] = __logf(s);
        }
      }
    }
    if (tid < 192) {
      int rr = tid / 12, d = tid % 12;
      jbuf[rr][d] = joints[(r0 + rr) * 12 + d];
    }
    __syncthreads();
    if (wv == 0) {
      bf16x8 ap[8];
      #pragma unroll
      for (int kt = 0; kt < 8; ++kt)
        ap[kt] = *reinterpret_cast<const bf16x8*>(&u1buf[lr][kt * 32 + lq * 8]);
      f32x4 acc = {0.f, 0.f, 0.f, 0.f};
      #pragma unroll
      for (int kt = 0; kt < 8; ++kt)
        acc = __builtin_amdgcn_mfma_f32_16x16x32_bf16(ap[kt], wo2f[kt], acc, 0, 0, 0);
      if (lr < 3) {
        #pragma unroll
        for (int r = 0; r < 4; ++r)
          objbuf[lq * 4 + r][lr] = acc[r] + bo2[lr];
      }
    }
    __syncthreads();
    for (int e = tid; e < 16 * 42; e += 256) {
      int rr = e / 42, pd = e % 42;
      float v;
      if (pd < 39) {
        float s = bfk[pd];
        #pragma unroll
        for (int d = 0; d < 12; ++d) s += jbuf[rr][d] * Wfk[pd * 12 + d];
        v = s;
      } else v = objbuf[rr][pd - 39];
      out0[(r0 + rr) * 42 + pd] = (v - pm[pd]) / ps[pd];
    }
    __syncthreads();
  }
}

extern "C" void kernel_launch(void* const* d_in, const int* in_sizes, int n_in,
                              void* d_out, int out_size, void* d_ws, size_t ws_size,
                              hipStream_t stream) {
  const float* z   = (const float*)d_in[0];
  const float* Whz = (const float*)d_in[1];
  const float* bhz = (const float*)d_in[2];
  const float* Wcz = (const float*)d_in[3];
  const float* bcz = (const float*)d_in[4];
  const float* Wih = (const float*)d_in[5];
  const float* Whh = (const float*)d_in[6];
  const float* bih = (const float*)d_in[7];
  const float* bhh = (const float*)d_in[8];
  const float* Wp1 = (const float*)d_in[9];
  const float* bp1 = (const float*)d_in[10];
  const float* Wp2 = (const float*)d_in[11];
  const float* bp2 = (const float*)d_in[12];
  const float* Wo1 = (const float*)d_in[13];
  const float* bo1 = (const float*)d_in[14];
  const float* Wo2 = (const float*)d_in[15];
  const float* bo2 = (const float*)d_in[16];
  const float* Wv  = (const float*)d_in[17];
  const float* bv  = (const float*)d_in[18];
  const float* Wfk = (const float*)d_in[19];
  const float* bfk = (const float*)d_in[20];
  const float* pm  = (const float*)d_in[21];
  const float* ps  = (const float*)d_in[22];
  const float* jlo = (const float*)d_in[23];
  const float* jhi = (const float*)d_in[24];
  const float* ddp = (const float*)d_in[25];

  char* ws = (char*)d_ws;
  float* tf    = (float*)(ws + OFF_TF);
  float* tconp = (float*)(ws + OFF_TCONP);
  float* zcp   = (float*)(ws + OFF_ZCP);
  float* h0    = (float*)(ws + OFF_H0);
  float* c0    = (float*)(ws + OFF_C0);
  bf16* Wcomb  = (bf16*)(ws + OFF_WCOMB);
  bf16* Wp1b   = (bf16*)(ws + OFF_WP1);
  bf16* Wp2b   = (bf16*)(ws + OFF_WP2);
  bf16* Wo1b   = (bf16*)(ws + OFF_WO1);
  bf16* Wo2b   = (bf16*)(ws + OFF_WO2);
  bf16* Wvb    = (bf16*)(ws + OFF_WV);
  u64* hxt     = (u64*)(ws + OFF_HX);
  bf16* Hseq   = (bf16*)(ws + OFF_HSEQ);

  float* out  = (float*)d_out;
  float* out0 = out;                 // graph_x_mu [B,T,42]
  float* outJ = out + 2150400;       // joint_traj [B,T,12]
  float* outA = out + 2764800;       // actions    [B,T,12]
  float* out3 = out + 3379200;       // log_sigma  [B,T,42]

  k_tfeat<<<11, 256, 0, stream>>>(tf);
  k_prep<<<2336, 256, 0, stream>>>(tf, Wih, z, bih, bhh, Whz, bhz, Wcz, bcz,
                                   tconp, zcp, h0, c0);
  k_cast<<<1744, 256, 0, stream>>>(Whh, Wih, Wp1, Wp2, Wo1, Wo2, Wv,
                                   Wcomb, Wp1b, Wp2b, Wo1b, Wo2b, Wvb);
  k_recur<<<32, 256, 0, stream>>>(zcp, tconp, h0, c0, Wcomb, Wp1b, Wp2b,
                                  bp1, bp2, jlo, jhi, ddp, hxt,
                                  Hseq, outJ, outA);
  k_post<<<320, 256, 0, stream>>>(Hseq, Wo1b, Wo2b, Wvb, bo1, bo2, bv,
                                  Wfk, bfk, pm, ps, outJ, out0, out3);
}

// Round 13
// 1078.648 us; speedup vs baseline: 4.6049x; 1.0143x over previous
//
#include <hip/hip_runtime.h>
#include <math.h>

#define B_ 256
#define T_ 200
#define H_ 256
#define DOF_ 12

typedef __bf16 bf16;
typedef __bf16 bf16x8 __attribute__((ext_vector_type(8)));
typedef float f32x4 __attribute__((ext_vector_type(4)));
typedef unsigned long long u64;

#define XK 288      // gate GEMM K: 256 h + 12 prev + 20 zero pad
#define XPAD 296
#define P1PAD 264

#define PI_D 3.14159265358979323846

// ---- workspace byte offsets (all 16B aligned) ----
#define OFF_TF     0u
#define OFF_TCONP  10400u
#define OFF_ZCP    829600u
#define OFF_H0     1878176u
#define OFF_C0     2140320u
#define OFF_WCOMB  2402464u
#define OFF_WP1    2992288u
#define OFF_WP2    3123360u
#define OFF_WO1    3131552u
#define OFF_WO2    3262624u
#define OFF_WV     3270816u
#define OFF_HX     3295392u    // 16 pairs * 2 slots * 2 halves * 128 * 4 * 16B = 512KB
#define OFF_HSEQ   3819680u    // 256*200*256*2 = 26214400 (end ~30.0MB)

__device__ __forceinline__ float sigf(float x) { return 1.f / (1.f + __expf(-x)); }
__device__ __forceinline__ float tanh_f(float x) {
  float a = fabsf(x);
  float e = __expf(-2.f * a);
  float t = (1.f - e) * __builtin_amdgcn_rcpf(1.f + e);
  return x < 0.f ? -t : t;
}

// light barrier: order LDS, leave global ops in flight
#define LBAR() asm volatile("s_waitcnt lgkmcnt(0)\n\ts_barrier" ::: "memory")

// ---------------- time features [T,13] ----------------
__global__ void k_tfeat(float* tf) {
  int i = blockIdx.x * blockDim.x + threadIdx.x;
  if (i >= T_ * 13) return;
  int t = i / 13, j = i % 13;
  float tv = (float)t / 199.f;
  float v;
  if (j == 0) v = tv;
  else {
    int k = (j - 1) >> 1;
    float f = (float)(1 << k);
    double arg = 2.0 * PI_D * (double)f * (double)tv;
    v = (j & 1) ? (float)sin(arg) : (float)cos(arg);
  }
  tf[i] = v;
}

// ------------- precompute tconp, zcp, h0, c0 (lane-packed layouts) -------------
__global__ void k_prep(const float* __restrict__ tf, const float* __restrict__ Wih,
                       const float* __restrict__ z,
                       const float* __restrict__ bih, const float* __restrict__ bhh,
                       const float* __restrict__ Whz, const float* __restrict__ bhz,
                       const float* __restrict__ Wcz, const float* __restrict__ bcz,
                       float* tconp, float* zcp, float* h0, float* c0) {
  int i = blockIdx.x * blockDim.x + threadIdx.x;
  if (i < 204800) {
    // tconp[t*1024 + half*512 + u_loc*4 + g]
    int g = i & 3, q = i >> 2;
    int m = q & 127, hm = (q >> 7) & 1, t = q >> 8;
    int n = g * 256 + 128 * hm + m;
    float s = 0.f;
    #pragma unroll
    for (int j = 0; j < 13; ++j) s += tf[t * 13 + j] * Wih[n * 89 + 76 + j];
    tconp[i] = s;
    return;
  }
  i -= 204800;
  if (i < 262144) {
    // zcp[((lbid*512 + tid512)*4 + g)*4 + r] ; tid512 = wv8*64 + ln, unit = 16*wv8 + lr
    int r = i & 3, g = (i >> 2) & 3, tid = (i >> 4) & 511;
    int half = (i >> 13) & 1, pairk = i >> 14;
    int wv = tid >> 6, lr = tid & 15, lq = (tid >> 4) & 3;
    int b = pairk * 16 + lq * 4 + r;
    int n = g * 256 + 128 * half + 16 * wv + lr;
    float s = bih[n] + bhh[n];
    for (int k = 0; k < 64; ++k) s += z[b * 64 + k] * Wih[n * 89 + 12 + k];
    zcp[i] = s;
    return;
  }
  i -= 262144;
  if (i < 65536) {
    int b = i / 256, u = i % 256;
    float s = bhz[u];
    for (int k = 0; k < 64; ++k) s += z[b * 64 + k] * Whz[u * 64 + k];
    h0[i] = s;
    return;
  }
  i -= 65536;
  if (i < 65536) {
    int b = i / 256, u = i % 256;
    float s = bcz[u];
    for (int k = 0; k < 64; ++k) s += z[b * 64 + k] * Wcz[u * 64 + k];
    c0[i] = s;
  }
}

// ------------- bf16 weight casts -------------
__global__ void k_cast(const float* __restrict__ Whh, const float* __restrict__ Wih,
                       const float* __restrict__ Wp1, const float* __restrict__ Wp2,
                       const float* __restrict__ Wo1, const float* __restrict__ Wo2,
                       const float* __restrict__ Wv,
                       bf16* Wcomb, bf16* Wp1b, bf16* Wp2b, bf16* Wo1b,
                       bf16* Wo2b, bf16* Wvb) {
  int i = blockIdx.x * blockDim.x + threadIdx.x;
  if (i < 294912) {
    int n = i / XK, k = i % XK;
    float v = (k < 256) ? Whh[n * 256 + k]
            : ((k < 268) ? Wih[n * 89 + (k - 256)] : 0.f);
    Wcomb[i] = (bf16)v;
    return;
  }
  i -= 294912;
  if (i < 65536) { Wp1b[i] = (bf16)Wp1[i]; return; }
  i -= 65536;
  if (i < 4096) { int r = i / 256; Wp2b[i] = (bf16)((r < 12) ? Wp2[i] : 0.f); return; }
  i -= 4096;
  if (i < 65536) { Wo1b[i] = (bf16)Wo1[i]; return; }
  i -= 65536;
  if (i < 4096) { int r = i / 256; Wo2b[i] = (bf16)((r < 3) ? Wo2[i] : 0.f); return; }
  i -= 4096;
  if (i < 12288) { int r = i / 256; Wvb[i] = (bf16)((r < 42) ? Wv[i] : 0.f); }
}

// ------- recurrent LSTM: 32 blocks (16 pairs x 2 halves), 256 thr, 4 waves -------
// 1 wave/SIMD -> 512 unified regs/wave: 288 AGPR (gate weights) + <=224 arch.
// Arch diet: all t-loop global accesses are SGPR-base + 32-bit lane offsets;
// zc AND tcon reloaded per step at gate-loop top (hidden under 72 MFMA).
__global__ __launch_bounds__(256, 1) void k_recur(
    const float* __restrict__ zcp, const float* __restrict__ tconp,
    const float* __restrict__ h0, const float* __restrict__ c0,
    const bf16* __restrict__ Wcomb, const bf16* __restrict__ Wp1b,
    const bf16* __restrict__ Wp2b,
    const float* __restrict__ bp1, const float* __restrict__ bp2,
    const float* __restrict__ jlo, const float* __restrict__ jhi,
    const float* __restrict__ ddp,
    u64* hxt,
    bf16* __restrict__ Hseq, float* __restrict__ outJ, float* __restrict__ outA) {
  __shared__ bf16 xbuf[16][XPAD];
  __shared__ bf16 w1[272][P1PAD];      // 0..255 Wp1, 256..271 Wp2
  __shared__ bf16 p1buf[16][P1PAD];
  const int tid = threadIdx.x;
  const int wv = tid >> 6, ln = tid & 63, lr = ln & 15, lq = ln >> 4;
  const int bid = blockIdx.x;
  const int pairk = ((bid >> 4) << 3) | (bid & 7);   // bid^8 shares this (same XCD)
  const int half = (bid >> 3) & 1;
  const int lbid = pairk * 2 + half;
  const int b0 = pairk * 16;

  // ---- one-time LDS fills (stride 256) ----
  for (int i = tid; i < 272 * 32; i += 256) {
    int r = i >> 5, c8 = (i & 31) * 8;
    bf16x8 v = (r < 256)
      ? *reinterpret_cast<const bf16x8*>(&Wp1b[r * 256 + c8])
      : *reinterpret_cast<const bf16x8*>(&Wp2b[(r - 256) * 256 + c8]);
    *reinterpret_cast<bf16x8*>(&w1[r][c8]) = v;
  }
  for (int i = tid; i < 16 * XPAD; i += 256) {
    int r = i / XPAD, c = i % XPAD;
    float v = 0.f;
    if (c < 256) v = h0[(b0 + r) * 256 + c];
    else if (c < 268) {
      int d = c - 256;
      float lo = jlo[d], hi = jhi[d];
      v = (ddp[d] - 0.5f * (hi + lo)) / (0.5f * (hi - lo));
    }
    xbuf[r][c] = (bf16)v;
  }

  // ---- ALL gate weights -> AGPRs (288 regs/lane) ----
  f32x4 wc[2][4][9];
  #pragma unroll
  for (int ji = 0; ji < 2; ++ji) {
    const int ug = 128 * half + 32 * wv + 16 * ji + lr;
    #pragma unroll
    for (int g = 0; g < 4; ++g)
      #pragma unroll
      for (int kt = 0; kt < 9; ++kt)
        wc[ji][g][kt] = *reinterpret_cast<const f32x4*>(
            &Wcomb[(size_t)(g * 256 + ug) * XK + kt * 32 + lq * 8]);
  }
  #pragma unroll
  for (int kt = 0; kt < 9; ++kt)
    asm volatile("" : "+a"(wc[0][0][kt]), "+a"(wc[0][1][kt]),
                      "+a"(wc[0][2][kt]), "+a"(wc[0][3][kt]),
                      "+a"(wc[1][0][kt]), "+a"(wc[1][1][kt]),
                      "+a"(wc[1][2][kt]), "+a"(wc[1][3][kt]));

  // ---- per-lane state (32-bit offsets; bases stay in SGPRs) ----
  const int ug0c = 128 * half + 32 * wv + lr;
  float c_reg[2][4];
  #pragma unroll
  for (int ji = 0; ji < 2; ++ji)
    #pragma unroll
    for (int r = 0; r < 4; ++r)
      c_reg[ji][r] = c0[(b0 + lq * 4 + r) * 256 + ug0c + 16 * ji];

  const int zc_i0 = (lbid * 512 + (2 * wv + 0) * 64 + ln) * 16;   // float idx
  const int zc_i1 = (lbid * 512 + (2 * wv + 1) * 64 + ln) * 16;
  int tc_i = half * 512 + (32 * wv + lr) * 4;                     // += 1024 / step
  int hs_i = ((b0 + lq * 4) * T_) * 256 + ug0c;                   // += 256 / step
  // hx offsets in u64 units: [pairk][slot][half][ul][lq][2]
  const int pw_i = pairk * 4096 + half * 1024 + (32 * wv + lr) * 8 + lq * 2;  // +128 ji, +2048 slot
  const int ru = 32 * wv + (ln >> 1);
  const int rcol = 128 * (half ^ 1) + ru;
  const int row0 = (ln & 1) * 8;
  const int pr_i = pairk * 4096 + (half ^ 1) * 1024 + ru * 8 + (ln & 1) * 4;  // +2048 slot

  float bp1r[4];
  #pragma unroll
  for (int jn = 0; jn < 4; ++jn) bp1r[jn] = bp1[64 * wv + 16 * jn + lr];
  float bp2r = 0.f, ddr = 0.f, lor = -1.f, hir = 1.f;
  if (lr < 12) { bp2r = bp2[lr]; ddr = ddp[lr]; lor = jlo[lr]; hir = jhi[lr]; }
  const float jmr = 0.5f * (hir + lor), jrr = 0.5f * (hir - lor);

  __syncthreads();
  bool dead = false;

  for (int t = 0; t < T_; ++t) {
    // ---- issue zc + tcon loads early (L2-resident; hidden under 72 MFMA) ----
    f32x4 zc0[4], zc1[4], tcv0, tcv1;
    #pragma unroll
    for (int g = 0; g < 4; ++g) {
      zc0[g] = *reinterpret_cast<const f32x4*>(zcp + zc_i0 + g * 4);
      zc1[g] = *reinterpret_cast<const f32x4*>(zcp + zc_i1 + g * 4);
    }
    tcv0 = *reinterpret_cast<const f32x4*>(tconp + tc_i);
    tcv1 = *reinterpret_cast<const f32x4*>(tconp + tc_i + 64);
    tc_i += 1024;

    // ---- gates: kt-outer, shared A fragment, AGPR weights, zero-init C ----
    f32x4 ac[2][4];
    #pragma unroll
    for (int ji = 0; ji < 2; ++ji)
      #pragma unroll
      for (int g = 0; g < 4; ++g) ac[ji][g] = (f32x4){0.f, 0.f, 0.f, 0.f};
    #pragma unroll
    for (int kt = 0; kt < 9; ++kt) {
      bf16x8 a = *reinterpret_cast<const bf16x8*>(&xbuf[lr][kt * 32 + lq * 8]);
      asm volatile("" : "+a"(wc[0][0][kt]), "+a"(wc[0][1][kt]),
                        "+a"(wc[0][2][kt]), "+a"(wc[0][3][kt]),
                        "+a"(wc[1][0][kt]), "+a"(wc[1][1][kt]),
                        "+a"(wc[1][2][kt]), "+a"(wc[1][3][kt]));
      #pragma unroll
      for (int ji = 0; ji < 2; ++ji)
        #pragma unroll
        for (int g = 0; g < 4; ++g)
          ac[ji][g] = __builtin_amdgcn_mfma_f32_16x16x32_bf16(
              a, __builtin_bit_cast(bf16x8, wc[ji][g][kt]), ac[ji][g], 0, 0, 0);
    }
    #pragma unroll
    for (int g = 0; g < 4; ++g) {
      ac[0][g] += zc0[g] + tcv0[g];
      ac[1][g] += zc1[g] + tcv1[g];
    }
    LBAR();  // all xbuf reads done before h overwrite

    // ---- LSTM elementwise + publish (tag-embedded) ----
    const unsigned int want = t + 1;
    bf16 hb[2][4];
    #pragma unroll
    for (int ji = 0; ji < 2; ++ji) {
      unsigned short s4[4];
      #pragma unroll
      for (int r = 0; r < 4; ++r) {
        float cn = sigf(ac[ji][1][r]) * c_reg[ji][r] + sigf(ac[ji][0][r]) * tanh_f(ac[ji][2][r]);
        float hn = sigf(ac[ji][3][r]) * tanh_f(cn);
        c_reg[ji][r] = cn;
        bf16 h = (bf16)hn;
        hb[ji][r] = h;
        s4[r] = __builtin_bit_cast(unsigned short, h);
      }
      u64 q0 = ((u64)want << 32) | (u64)s4[0] | ((u64)s4[1] << 16);
      u64 q1 = ((u64)want << 32) | (u64)s4[2] | ((u64)s4[3] << 16);
      int pwi = pw_i + ji * 128 + (t & 1) * 2048;
      __hip_atomic_store(hxt + pwi, q0, __ATOMIC_RELAXED, __HIP_MEMORY_SCOPE_AGENT);
      __hip_atomic_store(hxt + pwi + 1, q1, __ATOMIC_RELAXED, __HIP_MEMORY_SCOPE_AGENT);
    }
    // own h -> xbuf + Hseq (in the poll shadow)
    #pragma unroll
    for (int ji = 0; ji < 2; ++ji)
      #pragma unroll
      for (int r = 0; r < 4; ++r) {
        xbuf[lq * 4 + r][ug0c + 16 * ji] = hb[ji][r];
        Hseq[hs_i + r * (T_ * 256) + 16 * ji] = hb[ji][r];
      }
    hs_i += 256;

    // ---- batched poll: 4 u64 per lane ----
    u64 pq0, pq1, pq2, pq3;
    {
      const int pri = pr_i + (t & 1) * 2048;
      int guard = 1 << 16;
      for (;;) {
        pq0 = __hip_atomic_load(hxt + pri + 0, __ATOMIC_RELAXED, __HIP_MEMORY_SCOPE_AGENT);
        pq1 = __hip_atomic_load(hxt + pri + 1, __ATOMIC_RELAXED, __HIP_MEMORY_SCOPE_AGENT);
        pq2 = __hip_atomic_load(hxt + pri + 2, __ATOMIC_RELAXED, __HIP_MEMORY_SCOPE_AGENT);
        pq3 = __hip_atomic_load(hxt + pri + 3, __ATOMIC_RELAXED, __HIP_MEMORY_SCOPE_AGENT);
        int ok = ((unsigned)(pq0 >> 32) == want) & ((unsigned)(pq1 >> 32) == want) &
                 ((unsigned)(pq2 >> 32) == want) & ((unsigned)(pq3 >> 32) == want);
        if (__all(ok)) break;
        if (dead || --guard == 0) { dead = true; break; }
      }
    }
    xbuf[row0 + 0][rcol] = __builtin_bit_cast(bf16, (unsigned short)(pq0));
    xbuf[row0 + 1][rcol] = __builtin_bit_cast(bf16, (unsigned short)(pq0 >> 16));
    xbuf[row0 + 2][rcol] = __builtin_bit_cast(bf16, (unsigned short)(pq1));
    xbuf[row0 + 3][rcol] = __builtin_bit_cast(bf16, (unsigned short)(pq1 >> 16));
    xbuf[row0 + 4][rcol] = __builtin_bit_cast(bf16, (unsigned short)(pq2));
    xbuf[row0 + 5][rcol] = __builtin_bit_cast(bf16, (unsigned short)(pq2 >> 16));
    xbuf[row0 + 6][rcol] = __builtin_bit_cast(bf16, (unsigned short)(pq3));
    xbuf[row0 + 7][rcol] = __builtin_bit_cast(bf16, (unsigned short)(pq3 >> 16));
    LBAR();  // full h_new visible

    // ---- p1 = relu(h_new @ Wp1^T + bp1): wave owns 64 cols, kt-outer ----
    {
      f32x4 pa0 = {bp1r[0], bp1r[0], bp1r[0], bp1r[0]};
      f32x4 pa1 = {bp1r[1], bp1r[1], bp1r[1], bp1r[1]};
      f32x4 pa2 = {bp1r[2], bp1r[2], bp1r[2], bp1r[2]};
      f32x4 pa3 = {bp1r[3], bp1r[3], bp1r[3], bp1r[3]};
      #pragma unroll
      for (int kt = 0; kt < 8; ++kt) {
        bf16x8 av = *reinterpret_cast<const bf16x8*>(&xbuf[lr][kt * 32 + lq * 8]);
        bf16x8 b0v = *reinterpret_cast<const bf16x8*>(&w1[64 * wv + lr][kt * 32 + lq * 8]);
        bf16x8 b1v = *reinterpret_cast<const bf16x8*>(&w1[64 * wv + 16 + lr][kt * 32 + lq * 8]);
        bf16x8 b2v = *reinterpret_cast<const bf16x8*>(&w1[64 * wv + 32 + lr][kt * 32 + lq * 8]);
        bf16x8 b3v = *reinterpret_cast<const bf16x8*>(&w1[64 * wv + 48 + lr][kt * 32 + lq * 8]);
        pa0 = __builtin_amdgcn_mfma_f32_16x16x32_bf16(av, b0v, pa0, 0, 0, 0);
        pa1 = __builtin_amdgcn_mfma_f32_16x16x32_bf16(av, b1v, pa1, 0, 0, 0);
        pa2 = __builtin_amdgcn_mfma_f32_16x16x32_bf16(av, b2v, pa2, 0, 0, 0);
        pa3 = __builtin_amdgcn_mfma_f32_16x16x32_bf16(av, b3v, pa3, 0, 0, 0);
      }
      #pragma unroll
      for (int r = 0; r < 4; ++r) {
        p1buf[lq * 4 + r][64 * wv + lr]      = (bf16)fmaxf(pa0[r], 0.f);
        p1buf[lq * 4 + r][64 * wv + 16 + lr] = (bf16)fmaxf(pa1[r], 0.f);
        p1buf[lq * 4 + r][64 * wv + 32 + lr] = (bf16)fmaxf(pa2[r], 0.f);
        p1buf[lq * 4 + r][64 * wv + 48 + lr] = (bf16)fmaxf(pa3[r], 0.f);
      }
    }
    LBAR();  // p1 visible

    // ---- action head on wave 0 (redundant across halves; writes gated) ----
    if (wv == 0) {
      f32x4 acc = {0.f, 0.f, 0.f, 0.f};
      #pragma unroll
      for (int kt = 0; kt < 8; ++kt) {
        bf16x8 ap = *reinterpret_cast<const bf16x8*>(&p1buf[lr][kt * 32 + lq * 8]);
        bf16x8 w2 = *reinterpret_cast<const bf16x8*>(&w1[256 + lr][kt * 32 + lq * 8]);
        acc = __builtin_amdgcn_mfma_f32_16x16x32_bf16(ap, w2, acc, 0, 0, 0);
      }
      if (lr < 12) {
        #pragma unroll
        for (int r = 0; r < 4; ++r) {
          int b = lq * 4 + r;
          float act = tanh_f(acc[r] + bp2r);
          float curp = act * 0.25f + ddr;   // TRACK_ALPHA = 1
          float cl = fminf(fmaxf(curp, lor), hir);
          if (half == 0) {
            size_t o = ((size_t)(b0 + b) * T_ + t) * 12 + lr;
            outA[o] = act;
            outJ[o] = curp;
          }
          xbuf[b][256 + lr] = (bf16)((cl - jmr) / jrr);
        }
      }
    }
    LBAR();  // prev_norm visible for next step
  }
}

// ------------- post pass: obj head, sigma head, FK, normalize -------------
__global__ __launch_bounds__(256) void k_post(
    const bf16* __restrict__ Hseq, const bf16* __restrict__ Wo1b,
    const bf16* __restrict__ Wo2b, const bf16* __restrict__ Wvb,
    const float* __restrict__ bo1, const float* __restrict__ bo2,
    const float* __restrict__ bv,
    const float* __restrict__ Wfk, const float* __restrict__ bfk,
    const float* __restrict__ pm, const float* __restrict__ ps,
    const float* __restrict__ joints, float* __restrict__ out0,
    float* __restrict__ out3) {
  __shared__ bf16 u1buf[16][P1PAD];
  __shared__ float objbuf[16][3];
  __shared__ float jbuf[16][12];
  const int tid = threadIdx.x;
  const int wv = tid >> 6;
  const int ln = tid & 63;
  const int lr = ln & 15;
  const int lq = ln >> 4;

  bf16x8 wo1f[4][8];
  float bo1r[4];
  #pragma unroll
  for (int jn = 0; jn < 4; ++jn) {
    int n0 = wv * 64 + jn * 16;
    bo1r[jn] = bo1[n0 + lr];
    #pragma unroll
    for (int kt = 0; kt < 8; ++kt)
      wo1f[jn][kt] = *reinterpret_cast<const bf16x8*>(
          &Wo1b[(size_t)(n0 + lr) * 256 + kt * 32 + lq * 8]);
  }
  const int col = (wv - 1) * 16 + lr;
  bf16x8 wvf[8];
  float bvr = 0.f;
  if (wv >= 1) {
    #pragma unroll
    for (int kt = 0; kt < 8; ++kt)
      wvf[kt] = *reinterpret_cast<const bf16x8*>(
          &Wvb[(size_t)col * 256 + kt * 32 + lq * 8]);
    bvr = (col < 42) ? bv[col] : 0.f;
  }
  bf16x8 wo2f[8];
  if (wv == 0) {
    #pragma unroll
    for (int kt = 0; kt < 8; ++kt)
      wo2f[kt] = *reinterpret_cast<const bf16x8*>(
          &Wo2b[(size_t)lr * 256 + kt * 32 + lq * 8]);
  }

  for (int it = 0; it < 10; ++it) {
    int tt = blockIdx.x * 10 + it;
    size_t r0 = (size_t)tt * 16;
    bf16x8 ah[8];
    #pragma unroll
    for (int kt = 0; kt < 8; ++kt)
      ah[kt] = *reinterpret_cast<const bf16x8*>(&Hseq[(r0 + lr) * 256 + kt * 32 + lq * 8]);
    #pragma unroll
    for (int jn = 0; jn < 4; ++jn) {
      int n0 = wv * 64 + jn * 16;
      float bb = bo1r[jn];
      f32x4 acc = {bb, bb, bb, bb};
      #pragma unroll
      for (int kt = 0; kt < 8; ++kt)
        acc = __builtin_amdgcn_mfma_f32_16x16x32_bf16(ah[kt], wo1f[jn][kt], acc, 0, 0, 0);
      #pragma unroll
      for (int r = 0; r < 4; ++r)
        u1buf[lq * 4 + r][n0 + lr] = (bf16)fmaxf(acc[r], 0.f);
    }
    if (wv >= 1) {
      f32x4 acc = {bvr, bvr, bvr, bvr};
      #pragma unroll
      for (int kt = 0; kt < 8; ++kt)
        acc = __builtin_amdgcn_mfma_f32_16x16x32_bf16(ah[kt], wvf[kt], acc, 0, 0, 0);
      if (col < 42) {
        #pragma unroll
        for (int r = 0; r < 4; ++r) {
          float s = 0.05f + 0.45f * sigf(acc[r]);
          out3[(r0 + lq * 4 + r) * 42 + col] = __logf(s);
        }
      }
    }
    if (tid < 192) {
      int rr = tid / 12, d = tid % 12;
      jbuf[rr][d] = joints[(r0 + rr) * 12 + d];
    }
    __syncthreads();
    if (wv == 0) {
      bf16x8 ap[8];
      #pragma unroll
      for (int kt = 0; kt < 8; ++kt)
        ap[kt] = *reinterpret_cast<const bf16x8*>(&u1buf[lr][kt * 32 + lq * 8]);
      f32x4 acc = {0.f, 0.f, 0.f, 0.f};
      #pragma unroll
      for (int kt = 0; kt < 8; ++kt)
        acc = __builtin_amdgcn_mfma_f32_16x16x32_bf16(ap[kt], wo2f[kt], acc, 0, 0, 0);
      if (lr < 3) {
        #pragma unroll
        for (int r = 0; r < 4; ++r)
          objbuf[lq * 4 + r][lr] = acc[r] + bo2[lr];
      }
    }
    __syncthreads();
    for (int e = tid; e < 16 * 42; e += 256) {
      int rr = e / 42, pd = e % 42;
      float v;
      if (pd < 39) {
        float s = bfk[pd];
        #pragma unroll
        for (int d = 0; d < 12; ++d) s += jbuf[rr][d] * Wfk[pd * 12 + d];
        v = s;
      } else v = objbuf[rr][pd - 39];
      out0[(r0 + rr) * 42 + pd] = (v - pm[pd]) / ps[pd];
    }
    __syncthreads();
  }
}

extern "C" void kernel_launch(void* const* d_in, const int* in_sizes, int n_in,
                              void* d_out, int out_size, void* d_ws, size_t ws_size,
                              hipStream_t stream) {
  const float* z   = (const float*)d_in[0];
  const float* Whz = (const float*)d_in[1];
  const float* bhz = (const float*)d_in[2];
  const float* Wcz = (const float*)d_in[3];
  const float* bcz = (const float*)d_in[4];
  const float* Wih = (const float*)d_in[5];
  const float* Whh = (const float*)d_in[6];
  const float* bih = (const float*)d_in[7];
  const float* bhh = (const float*)d_in[8];
  const float* Wp1 = (const float*)d_in[9];
  const float* bp1 = (const float*)d_in[10];
  const float* Wp2 = (const float*)d_in[11];
  const float* bp2 = (const float*)d_in[12];
  const float* Wo1 = (const float*)d_in[13];
  const float* bo1 = (const float*)d_in[14];
  const float* Wo2 = (const float*)d_in[15];
  const float* bo2 = (const float*)d_in[16];
  const float* Wv  = (const float*)d_in[17];
  const float* bv  = (const float*)d_in[18];
  const float* Wfk = (const float*)d_in[19];
  const float* bfk = (const float*)d_in[20];
  const float* pm  = (const float*)d_in[21];
  const float* ps  = (const float*)d_in[22];
  const float* jlo = (const float*)d_in[23];
  const float* jhi = (const float*)d_in[24];
  const float* ddp = (const float*)d_in[25];

  char* ws = (char*)d_ws;
  float* tf    = (float*)(ws + OFF_TF);
  float* tconp = (float*)(ws + OFF_TCONP);
  float* zcp   = (float*)(ws + OFF_ZCP);
  float* h0    = (float*)(ws + OFF_H0);
  float* c0    = (float*)(ws + OFF_C0);
  bf16* Wcomb  = (bf16*)(ws + OFF_WCOMB);
  bf16* Wp1b   = (bf16*)(ws + OFF_WP1);
  bf16* Wp2b   = (bf16*)(ws + OFF_WP2);
  bf16* Wo1b   = (bf16*)(ws + OFF_WO1);
  bf16* Wo2b   = (bf16*)(ws + OFF_WO2);
  bf16* Wvb    = (bf16*)(ws + OFF_WV);
  u64* hxt     = (u64*)(ws + OFF_HX);
  bf16* Hseq   = (bf16*)(ws + OFF_HSEQ);

  float* out  = (float*)d_out;
  float* out0 = out;                 // graph_x_mu [B,T,42]
  float* outJ = out + 2150400;       // joint_traj [B,T,12]
  float* outA = out + 2764800;       // actions    [B,T,12]
  float* out3 = out + 3379200;       // log_sigma  [B,T,42]

  k_tfeat<<<11, 256, 0, stream>>>(tf);
  k_prep<<<2336, 256, 0, stream>>>(tf, Wih, z, bih, bhh, Whz, bhz, Wcz, bcz,
                                   tconp, zcp, h0, c0);
  k_cast<<<1744, 256, 0, stream>>>(Whh, Wih, Wp1, Wp2, Wo1, Wo2, Wv,
                                   Wcomb, Wp1b, Wp2b, Wo1b, Wo2b, Wvb);
  k_recur<<<32, 256, 0, stream>>>(zcp, tconp, h0, c0, Wcomb, Wp1b, Wp2b,
                                  bp1, bp2, jlo, jhi, ddp, hxt,
                                  Hseq, outJ, outA);
  k_post<<<320, 256, 0, stream>>>(Hseq, Wo1b, Wo2b, Wvb, bo1, bo2, bv,
                                  Wfk, bfk, pm, ps, outJ, out0, out3);
}

// Round 14
// 965.668 us; speedup vs baseline: 5.1436x; 1.1170x over previous
//
#include <hip/hip_runtime.h>
#include <math.h>

#define B_ 256
#define T_ 200
#define H_ 256
#define DOF_ 12

typedef __bf16 bf16;
typedef __bf16 bf16x8 __attribute__((ext_vector_type(8)));
typedef float f32x4 __attribute__((ext_vector_type(4)));
typedef unsigned long long u64;

#define XK 288      // gate GEMM K: 256 h + 12 prev + 20 zero pad
#define XPAD 296
#define P1PAD 264

#define PI_D 3.14159265358979323846

// ---- workspace byte offsets (all 16B aligned) ----
#define OFF_TF     0u
#define OFF_TCONP  10400u
#define OFF_ZCP    829600u
#define OFF_H0     1878176u
#define OFF_C0     2140320u
#define OFF_WCOMB  2402464u
#define OFF_WP1    2992288u
#define OFF_WP2    3123360u
#define OFF_WO1    3131552u
#define OFF_WO2    3262624u
#define OFF_WV     3270816u
#define OFF_HX     3295392u    // 16 grps * 2 slots * 4 quarters * 64 * 4 * 16B = 512KB
#define OFF_HSEQ   3819680u    // 256*200*256*2 = 26214400 (end ~30.0MB)

__device__ __forceinline__ float sigf(float x) { return 1.f / (1.f + __expf(-x)); }
__device__ __forceinline__ float tanh_f(float x) {
  float a = fabsf(x);
  float e = __expf(-2.f * a);
  float t = (1.f - e) * __builtin_amdgcn_rcpf(1.f + e);
  return x < 0.f ? -t : t;
}

// light barrier: order LDS, leave global ops in flight
#define LBAR() asm volatile("s_waitcnt lgkmcnt(0)\n\ts_barrier" ::: "memory")

// ---------------- time features [T,13] ----------------
__global__ void k_tfeat(float* tf) {
  int i = blockIdx.x * blockDim.x + threadIdx.x;
  if (i >= T_ * 13) return;
  int t = i / 13, j = i % 13;
  float tv = (float)t / 199.f;
  float v;
  if (j == 0) v = tv;
  else {
    int k = (j - 1) >> 1;
    float f = (float)(1 << k);
    double arg = 2.0 * PI_D * (double)f * (double)tv;
    v = (j & 1) ? (float)sin(arg) : (float)cos(arg);
  }
  tf[i] = v;
}

// ------------- precompute tconp, zcp, h0, c0 (lane-packed layouts) -------------
// tconp[t*1024 + u*4 + g]  (u = global unit 0..255)
// zcp[((bid*256 + tid)*4 + g)*4 + r]  (bid = quarter*16 + grp, 64 blocks x 256 thr)
__global__ void k_prep(const float* __restrict__ tf, const float* __restrict__ Wih,
                       const float* __restrict__ z,
                       const float* __restrict__ bih, const float* __restrict__ bhh,
                       const float* __restrict__ Whz, const float* __restrict__ bhz,
                       const float* __restrict__ Wcz, const float* __restrict__ bcz,
                       float* tconp, float* zcp, float* h0, float* c0) {
  int i = blockIdx.x * blockDim.x + threadIdx.x;
  if (i < 204800) {
    int g = i & 3, u = (i >> 2) & 255, t = i >> 10;
    int n = g * 256 + u;
    float s = 0.f;
    #pragma unroll
    for (int j = 0; j < 13; ++j) s += tf[t * 13 + j] * Wih[n * 89 + 76 + j];
    tconp[i] = s;
    return;
  }
  i -= 204800;
  if (i < 262144) {
    int r = i & 3, g = (i >> 2) & 3, tid = (i >> 4) & 255, bid = i >> 12;
    int quarter = bid >> 4, grp = bid & 15;
    int wv = tid >> 6, ln = tid & 63, lr = ln & 15, lq = (ln >> 4) & 3;
    int b = grp * 16 + lq * 4 + r;
    int n = g * 256 + 64 * quarter + 16 * wv + lr;
    float s = bih[n] + bhh[n];
    for (int k = 0; k < 64; ++k) s += z[b * 64 + k] * Wih[n * 89 + 12 + k];
    zcp[i] = s;
    return;
  }
  i -= 262144;
  if (i < 65536) {
    int b = i / 256, u = i % 256;
    float s = bhz[u];
    for (int k = 0; k < 64; ++k) s += z[b * 64 + k] * Whz[u * 64 + k];
    h0[i] = s;
    return;
  }
  i -= 65536;
  if (i < 65536) {
    int b = i / 256, u = i % 256;
    float s = bcz[u];
    for (int k = 0; k < 64; ++k) s += z[b * 64 + k] * Wcz[u * 64 + k];
    c0[i] = s;
  }
}

// ------------- bf16 weight casts -------------
__global__ void k_cast(const float* __restrict__ Whh, const float* __restrict__ Wih,
                       const float* __restrict__ Wp1, const float* __restrict__ Wp2,
                       const float* __restrict__ Wo1, const float* __restrict__ Wo2,
                       const float* __restrict__ Wv,
                       bf16* Wcomb, bf16* Wp1b, bf16* Wp2b, bf16* Wo1b,
                       bf16* Wo2b, bf16* Wvb) {
  int i = blockIdx.x * blockDim.x + threadIdx.x;
  if (i < 294912) {
    int n = i / XK, k = i % XK;
    float v = (k < 256) ? Whh[n * 256 + k]
            : ((k < 268) ? Wih[n * 89 + (k - 256)] : 0.f);
    Wcomb[i] = (bf16)v;
    return;
  }
  i -= 294912;
  if (i < 65536) { Wp1b[i] = (bf16)Wp1[i]; return; }
  i -= 65536;
  if (i < 4096) { int r = i / 256; Wp2b[i] = (bf16)((r < 12) ? Wp2[i] : 0.f); return; }
  i -= 4096;
  if (i < 65536) { Wo1b[i] = (bf16)Wo1[i]; return; }
  i -= 65536;
  if (i < 4096) { int r = i / 256; Wo2b[i] = (bf16)((r < 3) ? Wo2[i] : 0.f); return; }
  i -= 4096;
  if (i < 12288) { int r = i / 256; Wvb[i] = (bf16)((r < 42) ? Wv[i] : 0.f); }
}

// ------- recurrent LSTM: 64 blocks = 16 batch-groups x 4 unit-quarters -------
// 256 thr / 4 waves, 1 wave/SIMD -> 512-reg budget. Gate weights for the
// quarter = 144 AGPRs/lane + ~160 arch VGPRs: REAL slack, no spill. Wp1+Wp2 in
// LDS. 3-partner tag-embedded u64 relaxed agent-atomic h exchange (all four
// quarters of a group land on one XCD via bid = quarter*16 + grp).
__global__ __launch_bounds__(256, 1) void k_recur(
    const float* __restrict__ zcp, const float* __restrict__ tconp,
    const float* __restrict__ h0, const float* __restrict__ c0,
    const bf16* __restrict__ Wcomb, const bf16* __restrict__ Wp1b,
    const bf16* __restrict__ Wp2b,
    const float* __restrict__ bp1, const float* __restrict__ bp2,
    const float* __restrict__ jlo, const float* __restrict__ jhi,
    const float* __restrict__ ddp,
    u64* hxt,
    bf16* __restrict__ Hseq, float* __restrict__ outJ, float* __restrict__ outA) {
  __shared__ bf16 xbuf[16][XPAD];
  __shared__ bf16 w1[272][P1PAD];      // 0..255 Wp1, 256..271 Wp2
  __shared__ bf16 p1buf[16][P1PAD];
  const int tid = threadIdx.x;
  const int wv = tid >> 6, ln = tid & 63, lr = ln & 15, lq = ln >> 4;
  const int bid = blockIdx.x;
  const int quarter = bid >> 4, grp = bid & 15;   // same XCD for all quarters
  const int b0 = grp * 16;
  const int u_gl = 64 * quarter + 16 * wv + lr;

  // ---- one-time LDS fills (stride 256) ----
  for (int i = tid; i < 272 * 32; i += 256) {
    int r = i >> 5, c8 = (i & 31) * 8;
    bf16x8 v = (r < 256)
      ? *reinterpret_cast<const bf16x8*>(&Wp1b[r * 256 + c8])
      : *reinterpret_cast<const bf16x8*>(&Wp2b[(r - 256) * 256 + c8]);
    *reinterpret_cast<bf16x8*>(&w1[r][c8]) = v;
  }
  for (int i = tid; i < 16 * XPAD; i += 256) {
    int r = i / XPAD, c = i % XPAD;
    float v = 0.f;
    if (c < 256) v = h0[(b0 + r) * 256 + c];
    else if (c < 268) {
      int d = c - 256;
      float lo = jlo[d], hi = jhi[d];
      v = (ddp[d] - 0.5f * (hi + lo)) / (0.5f * (hi - lo));
    }
    xbuf[r][c] = (bf16)v;
  }

  // ---- quarter's gate weights -> AGPRs (144 regs/lane) ----
  f32x4 wc[4][9];
  #pragma unroll
  for (int g = 0; g < 4; ++g)
    #pragma unroll
    for (int kt = 0; kt < 9; ++kt)
      wc[g][kt] = *reinterpret_cast<const f32x4*>(
          &Wcomb[(size_t)(g * 256 + u_gl) * XK + kt * 32 + lq * 8]);
  #pragma unroll
  for (int kt = 0; kt < 9; ++kt)
    asm volatile("" : "+a"(wc[0][kt]), "+a"(wc[1][kt]),
                      "+a"(wc[2][kt]), "+a"(wc[3][kt]));

  // ---- per-lane state ----
  float c_reg[4];
  #pragma unroll
  for (int r = 0; r < 4; ++r) c_reg[r] = c0[(b0 + lq * 4 + r) * 256 + u_gl];
  const int zc_i = (bid * 256 + tid) * 16;
  int tc_i = u_gl * 4;                              // += 1024 / step
  int hs_i = ((b0 + lq * 4) * T_) * 256 + u_gl;     // += 256 / step
  // hx u64 offsets: entry (grp, slot, quarter, u_loc, lq) = 2 u64; slot stride 2048
  const int pw_i = (grp * 8 + quarter) * 512 + (16 * wv + lr) * 8 + lq * 2;
  const int ru = tid >> 2, rlq = tid & 3;           // reader entry (u_loc', lq')
  const int rrow0 = rlq * 4;
  const int q1 = (quarter + 1) & 3, q2 = (quarter + 2) & 3, q3 = (quarter + 3) & 3;
  const int pr1 = (grp * 8 + q1) * 512 + ru * 8 + rlq * 2;
  const int pr2 = (grp * 8 + q2) * 512 + ru * 8 + rlq * 2;
  const int pr3 = (grp * 8 + q3) * 512 + ru * 8 + rlq * 2;

  float bp1r[4];
  #pragma unroll
  for (int jn = 0; jn < 4; ++jn) bp1r[jn] = bp1[64 * wv + 16 * jn + lr];
  float bp2r = 0.f, ddr = 0.f, lor = -1.f, hir = 1.f;
  if (lr < 12) { bp2r = bp2[lr]; ddr = ddp[lr]; lor = jlo[lr]; hir = jhi[lr]; }
  const float jmr = 0.5f * (hir + lor), jrr = 0.5f * (hir - lor);

  __syncthreads();
  bool dead = false;

  for (int t = 0; t < T_; ++t) {
    // ---- issue zc + tcon loads early (L2-resident; hidden under 36 MFMA) ----
    f32x4 zc[4], tcv;
    #pragma unroll
    for (int g = 0; g < 4; ++g)
      zc[g] = *reinterpret_cast<const f32x4*>(zcp + zc_i + g * 4);
    tcv = *reinterpret_cast<const f32x4*>(tconp + tc_i);
    tc_i += 1024;

    // ---- gates: kt-outer, AGPR weights, zero-init C ----
    f32x4 ac[4];
    #pragma unroll
    for (int g = 0; g < 4; ++g) ac[g] = (f32x4){0.f, 0.f, 0.f, 0.f};
    #pragma unroll
    for (int kt = 0; kt < 9; ++kt) {
      bf16x8 a = *reinterpret_cast<const bf16x8*>(&xbuf[lr][kt * 32 + lq * 8]);
      asm volatile("" : "+a"(wc[0][kt]), "+a"(wc[1][kt]),
                        "+a"(wc[2][kt]), "+a"(wc[3][kt]));
      #pragma unroll
      for (int g = 0; g < 4; ++g)
        ac[g] = __builtin_amdgcn_mfma_f32_16x16x32_bf16(
            a, __builtin_bit_cast(bf16x8, wc[g][kt]), ac[g], 0, 0, 0);
    }
    #pragma unroll
    for (int g = 0; g < 4; ++g) ac[g] += zc[g] + tcv[g];
    LBAR();  // all xbuf reads done before h overwrite

    // ---- LSTM elementwise + publish (tag-embedded) ----
    const unsigned int want = t + 1;
    bf16 hb[4];
    unsigned short s4[4];
    #pragma unroll
    for (int r = 0; r < 4; ++r) {
      float cn = sigf(ac[1][r]) * c_reg[r] + sigf(ac[0][r]) * tanh_f(ac[2][r]);
      float hn = sigf(ac[3][r]) * tanh_f(cn);
      c_reg[r] = cn;
      bf16 h = (bf16)hn;
      hb[r] = h;
      s4[r] = __builtin_bit_cast(unsigned short, h);
    }
    {
      u64 q0 = ((u64)want << 32) | (u64)s4[0] | ((u64)s4[1] << 16);
      u64 qq1 = ((u64)want << 32) | (u64)s4[2] | ((u64)s4[3] << 16);
      int pwi = pw_i + (t & 1) * 2048;
      __hip_atomic_store(hxt + pwi, q0, __ATOMIC_RELAXED, __HIP_MEMORY_SCOPE_AGENT);
      __hip_atomic_store(hxt + pwi + 1, qq1, __ATOMIC_RELAXED, __HIP_MEMORY_SCOPE_AGENT);
    }
    // own h -> xbuf + Hseq (in the poll shadow)
    #pragma unroll
    for (int r = 0; r < 4; ++r) {
      xbuf[lq * 4 + r][u_gl] = hb[r];
      Hseq[hs_i + r * (T_ * 256)] = hb[r];
    }
    hs_i += 256;

    // ---- batched poll: 3 partners x 2 u64 per lane ----
    u64 pa0, pa1, pb0, pb1, pc0, pc1;
    {
      const int so = (t & 1) * 2048;
      int guard = 1 << 16;
      for (;;) {
        pa0 = __hip_atomic_load(hxt + pr1 + so, __ATOMIC_RELAXED, __HIP_MEMORY_SCOPE_AGENT);
        pa1 = __hip_atomic_load(hxt + pr1 + so + 1, __ATOMIC_RELAXED, __HIP_MEMORY_SCOPE_AGENT);
        pb0 = __hip_atomic_load(hxt + pr2 + so, __ATOMIC_RELAXED, __HIP_MEMORY_SCOPE_AGENT);
        pb1 = __hip_atomic_load(hxt + pr2 + so + 1, __ATOMIC_RELAXED, __HIP_MEMORY_SCOPE_AGENT);
        pc0 = __hip_atomic_load(hxt + pr3 + so, __ATOMIC_RELAXED, __HIP_MEMORY_SCOPE_AGENT);
        pc1 = __hip_atomic_load(hxt + pr3 + so + 1, __ATOMIC_RELAXED, __HIP_MEMORY_SCOPE_AGENT);
        int ok = ((unsigned)(pa0 >> 32) == want) & ((unsigned)(pa1 >> 32) == want) &
                 ((unsigned)(pb0 >> 32) == want) & ((unsigned)(pb1 >> 32) == want) &
                 ((unsigned)(pc0 >> 32) == want) & ((unsigned)(pc1 >> 32) == want);
        if (__all(ok)) break;
        if (dead || --guard == 0) { dead = true; break; }
      }
    }
    {
      int col1 = 64 * q1 + ru, col2 = 64 * q2 + ru, col3 = 64 * q3 + ru;
      xbuf[rrow0 + 0][col1] = __builtin_bit_cast(bf16, (unsigned short)(pa0));
      xbuf[rrow0 + 1][col1] = __builtin_bit_cast(bf16, (unsigned short)(pa0 >> 16));
      xbuf[rrow0 + 2][col1] = __builtin_bit_cast(bf16, (unsigned short)(pa1));
      xbuf[rrow0 + 3][col1] = __builtin_bit_cast(bf16, (unsigned short)(pa1 >> 16));
      xbuf[rrow0 + 0][col2] = __builtin_bit_cast(bf16, (unsigned short)(pb0));
      xbuf[rrow0 + 1][col2] = __builtin_bit_cast(bf16, (unsigned short)(pb0 >> 16));
      xbuf[rrow0 + 2][col2] = __builtin_bit_cast(bf16, (unsigned short)(pb1));
      xbuf[rrow0 + 3][col2] = __builtin_bit_cast(bf16, (unsigned short)(pb1 >> 16));
      xbuf[rrow0 + 0][col3] = __builtin_bit_cast(bf16, (unsigned short)(pc0));
      xbuf[rrow0 + 1][col3] = __builtin_bit_cast(bf16, (unsigned short)(pc0 >> 16));
      xbuf[rrow0 + 2][col3] = __builtin_bit_cast(bf16, (unsigned short)(pc1));
      xbuf[rrow0 + 3][col3] = __builtin_bit_cast(bf16, (unsigned short)(pc1 >> 16));
    }
    LBAR();  // full h_new visible

    // ---- p1 = relu(h_new @ Wp1^T + bp1): wave owns 64 cols, kt-outer ----
    {
      f32x4 pa[4];
      #pragma unroll
      for (int jn = 0; jn < 4; ++jn)
        pa[jn] = (f32x4){bp1r[jn], bp1r[jn], bp1r[jn], bp1r[jn]};
      #pragma unroll
      for (int kt = 0; kt < 8; ++kt) {
        bf16x8 av = *reinterpret_cast<const bf16x8*>(&xbuf[lr][kt * 32 + lq * 8]);
        #pragma unroll
        for (int jn = 0; jn < 4; ++jn) {
          bf16x8 bv = *reinterpret_cast<const bf16x8*>(
              &w1[64 * wv + 16 * jn + lr][kt * 32 + lq * 8]);
          pa[jn] = __builtin_amdgcn_mfma_f32_16x16x32_bf16(av, bv, pa[jn], 0, 0, 0);
        }
      }
      #pragma unroll
      for (int jn = 0; jn < 4; ++jn)
        #pragma unroll
        for (int r = 0; r < 4; ++r)
          p1buf[lq * 4 + r][64 * wv + 16 * jn + lr] = (bf16)fmaxf(pa[jn][r], 0.f);
    }
    LBAR();  // p1 visible

    // ---- action head on wave 0 (redundant across quarters; writes gated) ----
    if (wv == 0) {
      f32x4 acc = {0.f, 0.f, 0.f, 0.f};
      #pragma unroll
      for (int kt = 0; kt < 8; ++kt) {
        bf16x8 ap = *reinterpret_cast<const bf16x8*>(&p1buf[lr][kt * 32 + lq * 8]);
        bf16x8 w2 = *reinterpret_cast<const bf16x8*>(&w1[256 + lr][kt * 32 + lq * 8]);
        acc = __builtin_amdgcn_mfma_f32_16x16x32_bf16(ap, w2, acc, 0, 0, 0);
      }
      if (lr < 12) {
        #pragma unroll
        for (int r = 0; r < 4; ++r) {
          int b = lq * 4 + r;
          float act = tanh_f(acc[r] + bp2r);
          float curp = act * 0.25f + ddr;   // TRACK_ALPHA = 1
          float cl = fminf(fmaxf(curp, lor), hir);
          if (quarter == 0) {
            size_t o = ((size_t)(b0 + b) * T_ + t) * 12 + lr;
            outA[o] = act;
            outJ[o] = curp;
          }
          xbuf[b][256 + lr] = (bf16)((cl - jmr) / jrr);
        }
      }
    }
    LBAR();  // prev_norm visible for next step
  }
}

// ------------- post pass: obj head, sigma head, FK, normalize -------------
__global__ __launch_bounds__(256) void k_post(
    const bf16* __restrict__ Hseq, const bf16* __restrict__ Wo1b,
    const bf16* __restrict__ Wo2b, const bf16* __restrict__ Wvb,
    const float* __restrict__ bo1, const float* __restrict__ bo2,
    const float* __restrict__ bv,
    const float* __restrict__ Wfk, const float* __restrict__ bfk,
    const float* __restrict__ pm, const float* __restrict__ ps,
    const float* __restrict__ joints, float* __restrict__ out0,
    float* __restrict__ out3) {
  __shared__ bf16 u1buf[16][P1PAD];
  __shared__ float objbuf[16][3];
  __shared__ float jbuf[16][12];
  const int tid = threadIdx.x;
  const int wv = tid >> 6;
  const int ln = tid & 63;
  const int lr = ln & 15;
  const int lq = ln >> 4;

  bf16x8 wo1f[4][8];
  float bo1r[4];
  #pragma unroll
  for (int jn = 0; jn < 4; ++jn) {
    int n0 = wv * 64 + jn * 16;
    bo1r[jn] = bo1[n0 + lr];
    #pragma unroll
    for (int kt = 0; kt < 8; ++kt)
      wo1f[jn][kt] = *reinterpret_cast<const bf16x8*>(
          &Wo1b[(size_t)(n0 + lr) * 256 + kt * 32 + lq * 8]);
  }
  const int col = (wv - 1) * 16 + lr;
  bf16x8 wvf[8];
  float bvr = 0.f;
  if (wv >= 1) {
    #pragma unroll
    for (int kt = 0; kt < 8; ++kt)
      wvf[kt] = *reinterpret_cast<const bf16x8*>(
          &Wvb[(size_t)col * 256 + kt * 32 + lq * 8]);
    bvr = (col < 42) ? bv[col] : 0.f;
  }
  bf16x8 wo2f[8];
  if (wv == 0) {
    #pragma unroll
    for (int kt = 0; kt < 8; ++kt)
      wo2f[kt] = *reinterpret_cast<const bf16x8*>(
          &Wo2b[(size_t)lr * 256 + kt * 32 + lq * 8]);
  }

  for (int it = 0; it < 10; ++it) {
    int tt = blockIdx.x * 10 + it;
    size_t r0 = (size_t)tt * 16;
    bf16x8 ah[8];
    #pragma unroll
    for (int kt = 0; kt < 8; ++kt)
      ah[kt] = *reinterpret_cast<const bf16x8*>(&Hseq[(r0 + lr) * 256 + kt * 32 + lq * 8]);
    #pragma unroll
    for (int jn = 0; jn < 4; ++jn) {
      int n0 = wv * 64 + jn * 16;
      float bb = bo1r[jn];
      f32x4 acc = {bb, bb, bb, bb};
      #pragma unroll
      for (int kt = 0; kt < 8; ++kt)
        acc = __builtin_amdgcn_mfma_f32_16x16x32_bf16(ah[kt], wo1f[jn][kt], acc, 0, 0, 0);
      #pragma unroll
      for (int r = 0; r < 4; ++r)
        u1buf[lq * 4 + r][n0 + lr] = (bf16)fmaxf(acc[r], 0.f);
    }
    if (wv >= 1) {
      f32x4 acc = {bvr, bvr, bvr, bvr};
      #pragma unroll
      for (int kt = 0; kt < 8; ++kt)
        acc = __builtin_amdgcn_mfma_f32_16x16x32_bf16(ah[kt], wvf[kt], acc, 0, 0, 0);
      if (col < 42) {
        #pragma unroll
        for (int r = 0; r < 4; ++r) {
          float s = 0.05f + 0.45f * sigf(acc[r]);
          out3[(r0 + lq * 4 + r) * 42 + col] = __logf(s);
        }
      }
    }
    if (tid < 192) {
      int rr = tid / 12, d = tid % 12;
      jbuf[rr][d] = joints[(r0 + rr) * 12 + d];
    }
    __syncthreads();
    if (wv == 0) {
      bf16x8 ap[8];
      #pragma unroll
      for (int kt = 0; kt < 8; ++kt)
        ap[kt] = *reinterpret_cast<const bf16x8*>(&u1buf[lr][kt * 32 + lq * 8]);
      f32x4 acc = {0.f, 0.f, 0.f, 0.f};
      #pragma unroll
      for (int kt = 0; kt < 8; ++kt)
        acc = __builtin_amdgcn_mfma_f32_16x16x32_bf16(ap[kt], wo2f[kt], acc, 0, 0, 0);
      if (lr < 3) {
        #pragma unroll
        for (int r = 0; r < 4; ++r)
          objbuf[lq * 4 + r][lr] = acc[r] + bo2[lr];
      }
    }
    __syncthreads();
    for (int e = tid; e < 16 * 42; e += 256) {
      int rr = e / 42, pd = e % 42;
      float v;
      if (pd < 39) {
        float s = bfk[pd];
        #pragma unroll
        for (int d = 0; d < 12; ++d) s += jbuf[rr][d] * Wfk[pd * 12 + d];
        v = s;
      } else v = objbuf[rr][pd - 39];
      out0[(r0 + rr) * 42 + pd] = (v - pm[pd]) / ps[pd];
    }
    __syncthreads();
  }
}

extern "C" void kernel_launch(void* const* d_in, const int* in_sizes, int n_in,
                              void* d_out, int out_size, void* d_ws, size_t ws_size,
                              hipStream_t stream) {
  const float* z   = (const float*)d_in[0];
  const float* Whz = (const float*)d_in[1];
  const float* bhz = (const float*)d_in[2];
  const float* Wcz = (const float*)d_in[3];
  const float* bcz = (const float*)d_in[4];
  const float* Wih = (const float*)d_in[5];
  const float* Whh = (const float*)d_in[6];
  const float* bih = (const float*)d_in[7];
  const float* bhh = (const float*)d_in[8];
  const float* Wp1 = (const float*)d_in[9];
  const float* bp1 = (const float*)d_in[10];
  const float* Wp2 = (const float*)d_in[11];
  const float* bp2 = (const float*)d_in[12];
  const float* Wo1 = (const float*)d_in[13];
  const float* bo1 = (const float*)d_in[14];
  const float* Wo2 = (const float*)d_in[15];
  const float* bo2 = (const float*)d_in[16];
  const float* Wv  = (const float*)d_in[17];
  const float* bv  = (const float*)d_in[18];
  const float* Wfk = (const float*)d_in[19];
  const float* bfk = (const float*)d_in[20];
  const float* pm  = (const float*)d_in[21];
  const float* ps  = (const float*)d_in[22];
  const float* jlo = (const float*)d_in[23];
  const float* jhi = (const float*)d_in[24];
  const float* ddp = (const float*)d_in[25];

  char* ws = (char*)d_ws;
  float* tf    = (float*)(ws + OFF_TF);
  float* tconp = (float*)(ws + OFF_TCONP);
  float* zcp   = (float*)(ws + OFF_ZCP);
  float* h0    = (float*)(ws + OFF_H0);
  float* c0    = (float*)(ws + OFF_C0);
  bf16* Wcomb  = (bf16*)(ws + OFF_WCOMB);
  bf16* Wp1b   = (bf16*)(ws + OFF_WP1);
  bf16* Wp2b   = (bf16*)(ws + OFF_WP2);
  bf16* Wo1b   = (bf16*)(ws + OFF_WO1);
  bf16* Wo2b   = (bf16*)(ws + OFF_WO2);
  bf16* Wvb    = (bf16*)(ws + OFF_WV);
  u64* hxt     = (u64*)(ws + OFF_HX);
  bf16* Hseq   = (bf16*)(ws + OFF_HSEQ);

  float* out  = (float*)d_out;
  float* out0 = out;                 // graph_x_mu [B,T,42]
  float* outJ = out + 2150400;       // joint_traj [B,T,12]
  float* outA = out + 2764800;       // actions    [B,T,12]
  float* out3 = out + 3379200;       // log_sigma  [B,T,42]

  k_tfeat<<<11, 256, 0, stream>>>(tf);
  k_prep<<<2336, 256, 0, stream>>>(tf, Wih, z, bih, bhh, Whz, bhz, Wcz, bcz,
                                   tconp, zcp, h0, c0);
  k_cast<<<1744, 256, 0, stream>>>(Whh, Wih, Wp1, Wp2, Wo1, Wo2, Wv,
                                   Wcomb, Wp1b, Wp2b, Wo1b, Wo2b, Wvb);
  k_recur<<<64, 256, 0, stream>>>(zcp, tconp, h0, c0, Wcomb, Wp1b, Wp2b,
                                  bp1, bp2, jlo, jhi, ddp, hxt,
                                  Hseq, outJ, outA);
  k_post<<<320, 256, 0, stream>>>(Hseq, Wo1b, Wo2b, Wvb, bo1, bo2, bv,
                                  Wfk, bfk, pm, ps, outJ, out0, out3);
}